// Round 7
// baseline (352.733 us; speedup 1.0000x reference)
//
#include <hip/hip_runtime.h>
#include <math.h>

#define FW 50
#define FH 38
#define NPIX 1900   // 38*50
#define NROIS 512

// padded layouts
#define CSH 2470    // horizontal-consumed: [c][y*65 + x + t], width 65 = 50+15
#define CSV 2650    // vertical-consumed:   [c][x*53 + y + t], height 53 = 38+15

typedef __bf16 bf16x8 __attribute__((ext_vector_type(8)));
typedef float  f32x4  __attribute__((ext_vector_type(4)));
typedef float  f32x16 __attribute__((ext_vector_type(16)));

__device__ __forceinline__ unsigned short f2b(float f) {
    unsigned int u = __float_as_uint(f);
    unsigned int r = (u + 0x7fffu + ((u >> 16) & 1u)) >> 16;   // RNE
    return (unsigned short)r;
}

// ---------------------------------------------------------------------------
// prep_all: ALL preprocessing in ONE dispatch (launch overhead dominated).
// ---------------------------------------------------------------------------
#define PB0 21200            // xpad_v          : 2048*CSV elems
#define PB1 (PB0 + 19760)    // xpad_h          : 2048*CSH
#define PB2 (PB1 + 641)      // zero c1colb+row : 1,310,848 shorts / 8
#define PB3 (PB2 + 8192)     // repack big0     : 8,388,608 / 4
#define PB4 (PB3 + 8192)     // repack big1
#define PB5 (PB4 + 1960)     // repack wc16     : 2,007,040 / 4
#define PB6 (PB5 + 1960)     // repack wr16
#define PB7 (PB6 + 4096)     // cvt_pad fc1     : 2048*512
#define PB8 (PB7 + 648)      // cvt loc         : 663,552 / 4
#define PB9 (PB8 + 162)      // cvt score       : 165,888 / 4
#define PREP_BLOCKS PB9

__device__ __forceinline__ void repack4(
    const float* __restrict__ w, unsigned short* __restrict__ out,
    int gid, int n)
{
    int o = gid * 4;
    if (o >= n) return;
    int t0 = o & 15;
    int oc = o >> 4;
    ushort4 v;
    v.x = (t0     < 15) ? f2b(w[oc * 15 + t0    ]) : (unsigned short)0;
    v.y = (t0 + 1 < 15) ? f2b(w[oc * 15 + t0 + 1]) : (unsigned short)0;
    v.z = (t0 + 2 < 15) ? f2b(w[oc * 15 + t0 + 2]) : (unsigned short)0;
    v.w = (t0 + 3 < 15) ? f2b(w[oc * 15 + t0 + 3]) : (unsigned short)0;
    *(ushort4*)(out + o) = v;
}

__device__ __forceinline__ void cvt4(
    const float* __restrict__ in, unsigned short* __restrict__ out, int gid)
{
    int i = gid * 4;
    float4 v = *(const float4*)(in + i);
    ushort4 r;
    r.x = f2b(v.x); r.y = f2b(v.y); r.z = f2b(v.z); r.w = f2b(v.w);
    *(ushort4*)(out + i) = r;
}

__global__ __launch_bounds__(256) void prep_all(
    const float* __restrict__ x,
    const float* __restrict__ w_col_max, const float* __restrict__ w_row_max,
    const float* __restrict__ w_col,     const float* __restrict__ w_row,
    const float* __restrict__ w_fc1,
    const float* __restrict__ w_loc,     const float* __restrict__ w_score,
    unsigned short* __restrict__ XvU,    unsigned short* __restrict__ XhU,
    unsigned short* __restrict__ zeroDst,
    unsigned short* __restrict__ wbig0,  unsigned short* __restrict__ wbig1,
    unsigned short* __restrict__ wc16,   unsigned short* __restrict__ wr16,
    unsigned short* __restrict__ wfc1b,
    unsigned short* __restrict__ wlocb,  unsigned short* __restrict__ wscoreb)
{
    const int b = blockIdx.x;
    const int tid = threadIdx.x;
    if (b < PB0) {                                  // xpad_v
        int idx = b * 256 + tid;
        if (idx >= 2048 * CSV) return;
        int c = idx / CSV;
        int rem = idx - c * CSV;
        int xx = rem / 53;
        int yc = rem - xx * 53 - 7;
        unsigned short v = 0;
        if (yc >= 0 && yc < FH) v = f2b(x[(c * FH + yc) * FW + xx]);
        XvU[idx] = v;
    } else if (b < PB1) {                           // xpad_h
        int idx = (b - PB0) * 256 + tid;
        if (idx >= 2048 * CSH) return;
        int c = idx / CSH;
        int rem = idx - c * CSH;
        int y = rem / 65;
        int xc = rem - y * 65 - 7;
        unsigned short v = 0;
        if (xc >= 0 && xc < FW) v = f2b(x[(c * FH + y) * FW + xc]);
        XhU[idx] = v;
    } else if (b < PB2) {                           // zero pad buffers
        int i = ((b - PB1) * 256 + tid) * 8;
        if (i < 1310848) { uint4 z; z.x = z.y = z.z = z.w = 0u; *(uint4*)(zeroDst + i) = z; }
    } else if (b < PB3) {                           // repack w_col_max
        repack4(w_col_max, wbig0, (b - PB2) * 256 + tid, 8388608);
    } else if (b < PB4) {                           // repack w_row_max
        repack4(w_row_max, wbig1, (b - PB3) * 256 + tid, 8388608);
    } else if (b < PB5) {                           // repack w_col
        repack4(w_col, wc16, (b - PB4) * 256 + tid, 2007040);
    } else if (b < PB6) {                           // repack w_row
        repack4(w_row, wr16, (b - PB5) * 256 + tid, 2007040);
    } else if (b < PB7) {                           // cvt_pad w_fc1 (490 -> 512)
        int idx = (b - PB6) * 256 + tid;
        int rw = idx >> 9, k = idx & 511;
        wfc1b[idx] = (k < 490) ? f2b(w_fc1[(size_t)rw * 490 + k]) : (unsigned short)0;
    } else if (b < PB8) {                           // cvt w_loc
        cvt4(w_loc, wlocb, (b - PB7) * 256 + tid);
    } else {                                        // cvt w_score
        cvt4(w_score, wscoreb, (b - PB8) * 256 + tid);
    }
}

// ---------------------------------------------------------------------------
// DUAL tap-padded bf16 conv-as-GEMM, v7: R0-proven iteration structure
// (128x128 block tile, 4 waves 2x2 of 64x64, BK=32, dbuf LDS, one
// __syncthreads per K-step, linear blockIdx) with TWO changes:
//  1. LDS rows are 32 shorts (64B, no pad) with XOR chunk swizzle
//     byte = row*64 + ((chunk ^ ((row>>1)&3))<<4)  [R1/R2-verified pattern].
//     -> LDS/block 40.96KB -> 32.77KB: 5 blocks/CU (was 3.75) for more
//        cross-block overlap of the LDS-pipe-bound iteration; read/write
//        bank mapping uniform (kills the [.][40] 4-way read aliasing).
//  2. s_setprio(1) around the MFMA cluster (co-resident blocks run at
//     independent phases -> scheduler can favor MFMA-ready waves).
// C/D layout (32x32): col=lane&31, row=(reg&3)+8*(reg>>2)+4*(lane>>5).
// ---------------------------------------------------------------------------
__device__ __forceinline__ int swz(int row, int chunk) {
    return row * 64 + ((chunk ^ ((row >> 1) & 3)) << 4);   // byte offset
}

__global__ __launch_bounds__(256) void conv_dual(
    const unsigned short* __restrict__ W0, const unsigned short* __restrict__ X0,
    float* __restrict__ P0, int CS0, int yMul0, int xMul0,
    const unsigned short* __restrict__ W1, const unsigned short* __restrict__ X1,
    float* __restrict__ P1, int CS1, int yMul1, int xMul1,
    int M, int Kp, int Mpad,
    int zMask, int zBits, int yMask, int xShift, int halfGrid)
{
    int id = blockIdx.x;
    const unsigned short* Wt; const unsigned short* Xp; float* P;
    int CS, yMul, xMul;
    if (id < halfGrid) {
        Wt = W0; Xp = X0; P = P0; CS = CS0; yMul = yMul0; xMul = xMul0;
    } else {
        id -= halfGrid;
        Wt = W1; Xp = X1; P = P1; CS = CS1; yMul = yMul1; xMul = xMul1;
    }
    const int zt = id & zMask;
    const int yt = (id >> zBits) & yMask;
    const int xt = id >> xShift;
    const int nsplit = zMask + 1;

    const int Ks = Kp / nsplit;
    const int k0 = zt * Ks;
    const int tid  = threadIdx.x;
    const int lane = tid & 63;
    const int wave = tid >> 6;
    const int mbase = yt * 128;
    const int pbase = xt * 128;

    __shared__ unsigned short As[2][4096];   // 128 rows x 32 shorts, swizzled
    __shared__ unsigned short Bt[2][4096];

    // A staging: 128 rows x 32 k; thread: row=tid>>1, k-half=(tid&1)*16
    const int a_row  = tid >> 1;
    const int a_half = tid & 1;
    const int a_src = min(mbase + a_row, M - 1);   // clamp; dups land in Mpad pad
    const unsigned short* Abase = Wt + (size_t)a_src * Kp + a_half * 16;
    const int aw0 = swz(a_row, a_half * 2);
    const int aw1 = swz(a_row, a_half * 2 + 1);

    // B staging: 128 pixels x 32 k; thread: pixel=tid>>1, channel-half=tid&1
    const int b_pix = tid >> 1;
    const int bh    = tid & 1;
    int p = pbase + b_pix;
    if (p > NPIX - 1) p = NPIX - 1;          // clamp (stores guarded)
    const int py = p / FW, px = p - py * FW;
    const int pixBase = py * yMul + px * xMul;
    const unsigned* __restrict__ Bdw = (const unsigned*)Xp;
    const int bw0 = swz(b_pix, bh * 2);
    const int bw1 = swz(b_pix, bh * 2 + 1);

    f32x16 acc[2][2];
#pragma unroll
    for (int i = 0; i < 2; ++i)
#pragma unroll
        for (int j = 0; j < 2; ++j)
#pragma unroll
            for (int r = 0; r < 16; ++r) acc[i][j][r] = 0.f;

    const int wy = (wave >> 1) * 64;
    const int wx = (wave & 1) * 64;
    const int l5 = lane & 31;
    const int hi = lane >> 5;

    // precomputed swizzled frag-read byte offsets (static in the loop)
    int aoff[2][2], boff[2][2];
#pragma unroll
    for (int i = 0; i < 2; ++i)
#pragma unroll
        for (int kk = 0; kk < 2; ++kk) {
            aoff[i][kk] = swz(wy + i * 32 + l5, kk * 2 + hi);
            boff[i][kk] = swz(wx + i * 32 + l5, kk * 2 + hi);
        }

    uint4 aR0, aR1;
    unsigned d[9];

    auto loadA = [&](int kt) {
        aR0 = *(const uint4*)(Abase + kt);
        aR1 = *(const uint4*)(Abase + kt + 8);
    };
    auto loadB = [&](int kt) {
        const int cg = (kt >> 4) + bh;               // this thread's channel
        const unsigned base = ((unsigned)(cg * CS + pixBase)) >> 1;
#pragma unroll
        for (int j = 0; j < 9; ++j) d[j] = Bdw[base + j];
    };

    loadA(k0); loadB(k0);
    const unsigned sh = ((unsigned)(pixBase & 1)) << 4;  // CS even -> parity fixed

    int buf = 0;
    for (int kt = k0; kt < k0 + Ks; kt += 32) {
        unsigned ob[8];
#pragma unroll
        for (int j = 0; j < 8; ++j)
            ob[j] = __builtin_amdgcn_alignbit(d[j + 1], d[j], sh);
        *(uint4*)((char*)As[buf] + aw0) = aR0;
        *(uint4*)((char*)As[buf] + aw1) = aR1;
        *(uint4*)((char*)Bt[buf] + bw0) = *(uint4*)&ob[0];
        *(uint4*)((char*)Bt[buf] + bw1) = *(uint4*)&ob[4];
        __syncthreads();

        if (kt + 32 < k0 + Ks) { loadA(kt + 32); loadB(kt + 32); }

        const char* Ab = (const char*)As[buf];
        const char* Bb = (const char*)Bt[buf];
        bf16x8 af[2][2], bfr[2][2];
#pragma unroll
        for (int i = 0; i < 2; ++i)
#pragma unroll
            for (int kk = 0; kk < 2; ++kk) {
                af[i][kk]  = __builtin_bit_cast(bf16x8, *(const uint4*)(Ab + aoff[i][kk]));
                bfr[i][kk] = __builtin_bit_cast(bf16x8, *(const uint4*)(Bb + boff[i][kk]));
            }
        __builtin_amdgcn_s_setprio(1);
#pragma unroll
        for (int kk = 0; kk < 2; ++kk)
#pragma unroll
            for (int i = 0; i < 2; ++i)
#pragma unroll
                for (int j = 0; j < 2; ++j)
                    acc[i][j] = __builtin_amdgcn_mfma_f32_32x32x16_bf16(
                        af[i][kk], bfr[j][kk], acc[i][j], 0, 0, 0);
        __builtin_amdgcn_s_setprio(0);
        buf ^= 1;
    }

    float* Pp = P + (size_t)zt * Mpad * NPIX;
#pragma unroll
    for (int i = 0; i < 2; ++i) {
        const int mb = mbase + wy + i * 32 + (lane >> 5) * 4;
#pragma unroll
        for (int j = 0; j < 2; ++j) {
            const int pp = pbase + wx + j * 32 + l5;
            if (pp < NPIX) {
#pragma unroll
                for (int r = 0; r < 16; ++r) {
                    const int m = mb + (r & 3) + 8 * (r >> 2);
                    Pp[(size_t)m * NPIX + pp] = acc[i][j][r];
                }
            }
        }
    }
}

// conv1 dual reduce: both paths' partials + bias -> bf16 padded layouts.
// 4 pixels per thread, float4 partial loads. halfGrid = 475 blocks per path.
__global__ void reduce_pad_dual(
    const float* __restrict__ P0, const float* __restrict__ bias0,
    unsigned short* __restrict__ out0, int CS0, int yM0, int xM0,
    const float* __restrict__ P1, const float* __restrict__ bias1,
    unsigned short* __restrict__ out1, int CS1, int yM1, int xM1,
    int Mpad, int nsplit, int M, int halfGrid)
{
    int b = blockIdx.x;
    const float* P; const float* bias; unsigned short* outb;
    int CS, yMul, xMul;
    if (b < halfGrid) { P = P0; bias = bias0; outb = out0; CS = CS0; yMul = yM0; xMul = xM0; }
    else { b -= halfGrid; P = P1; bias = bias1; outb = out1; CS = CS1; yMul = yM1; xMul = xM1; }
    int idx4 = b * 256 + threadIdx.x;
    if (idx4 >= M * 475) return;
    int o = idx4 / 475;
    int p = (idx4 - o * 475) * 4;
    float bv = bias[o];
    f32x4 s = {bv, bv, bv, bv};
    for (int sp = 0; sp < nsplit; ++sp)
        s += *(const f32x4*)&P[((size_t)sp * Mpad + o) * NPIX + p];
#pragma unroll
    for (int e = 0; e < 4; ++e) {
        int pe = p + e;
        int y = pe / FW, x = pe - y * FW;
        outb[(size_t)o * CS + y * yMul + x * xMul + 7] = f2b(s[e]);
    }
}

// conv2 dual reduce: h = relu(sum P0 + sum P1 + b_col + b_row), fp32 raster.
__global__ void reduce_bias_dual(
    const float* __restrict__ P0, const float* __restrict__ P1,
    int Mpad, int nsplit,
    const float* __restrict__ bias0, const float* __restrict__ bias1,
    int M, float* __restrict__ outf)
{
    int idx4 = blockIdx.x * 256 + threadIdx.x;
    if (idx4 >= M * 475) return;
    int o = idx4 / 475;
    int p = (idx4 - o * 475) * 4;
    float bv = bias0[o] + bias1[o];
    f32x4 s = {bv, bv, bv, bv};
    for (int sp = 0; sp < nsplit; ++sp) {
        s += *(const f32x4*)&P0[((size_t)sp * Mpad + o) * NPIX + p];
        s += *(const f32x4*)&P1[((size_t)sp * Mpad + o) * NPIX + p];
    }
#pragma unroll
    for (int e = 0; e < 4; ++e) s[e] = fmaxf(s[e], 0.f);
    *(f32x4*)&outf[(size_t)o * NPIX + p] = s;
}

// ---------------------------------------------------------------------------
// PSROI bilinear pooling (fp32 h) -> bf16 pooled [512][512] zero-padded
// ---------------------------------------------------------------------------
__global__ __launch_bounds__(512) void pool_kernel(
    const float* __restrict__ h, const float* __restrict__ rois,
    unsigned short* __restrict__ pooledb)
{
    int n = blockIdx.x;
    int k = threadIdx.x;
    if (k >= 490) {
        pooledb[(size_t)n * 512 + k] = 0;
        return;
    }
    float x1 = rois[n * 4 + 0], y1 = rois[n * 4 + 1];
    float x2 = rois[n * 4 + 2], y2 = rois[n * 4 + 3];
    float xmin = x1 * (1.f / 16.f) / 50.f;
    float ymin = y1 * (1.f / 16.f) / 38.f;
    float xmax = x2 * (1.f / 16.f) / 50.f;
    float ymax = y2 * (1.f / 16.f) / 38.f;
    float step_x = (xmax - xmin) / 7.f;
    float step_y = (ymax - ymin) / 7.f;
    int bin = k / 10;
    int bi = bin / 7, bj = bin - bi * 7;
    const float* ch = h + (size_t)k * NPIX;
    float m = -INFINITY;
#pragma unroll
    for (int sy = 0; sy < 2; ++sy) {
        float yv = (ymin + (float)(bi + sy) * step_y) * 37.f;
        float y0 = floorf(yv);
        float fy = yv - y0;
        int yi0 = min(max((int)y0, 0), 37);
        int yi1 = min(max((int)y0 + 1, 0), 37);
#pragma unroll
        for (int sx = 0; sx < 2; ++sx) {
            float xv = (xmin + (float)(bj + sx) * step_x) * 49.f;
            float x0 = floorf(xv);
            float fx = xv - x0;
            int xi0 = min(max((int)x0, 0), 49);
            int xi1 = min(max((int)x0 + 1, 0), 49);
            float v00 = ch[yi0 * FW + xi0], v01 = ch[yi0 * FW + xi1];
            float v10 = ch[yi1 * FW + xi0], v11 = ch[yi1 * FW + xi1];
            float top = v00 + (v01 - v00) * fx;
            float bot = v10 + (v11 - v10) * fx;
            float val = top + (bot - top) * fy;
            m = fmaxf(m, val);
        }
    }
    pooledb[(size_t)n * 512 + k] = f2b(m);
}

// ---------------------------------------------------------------------------
// bf16 MFMA NT GEMM (FC): A = weights [M][Kld], B = acts [512][Kld], split-K.
// ---------------------------------------------------------------------------
__device__ __forceinline__ void fc_body(
    const unsigned short* __restrict__ Wb,
    const unsigned short* __restrict__ Act,
    float* __restrict__ P, int M, int Kld, int Mpad, int nsplit,
    int bx, int by, int bz,
    unsigned short (*As)[40], unsigned short (*Bs)[40])
{
    const int Ks = Kld / nsplit;
    const int k0 = bz * Ks;
    const int tid  = threadIdx.x;
    const int lane = tid & 63;
    const int wave = tid >> 6;
    const int mbase = bx * 64;
    const int nbase = by * 64;

    const int s_r  = tid >> 2;
    const int s_k8 = (tid & 3) << 3;
    const int a_row = mbase + s_r;
    const bool a_ok = a_row < M;
    const unsigned short* Abase = Wb + (size_t)a_row * Kld + s_k8;
    const unsigned short* Bbase = Act + (size_t)(nbase + s_r) * Kld + s_k8;

    f32x4 acc[2][2];
#pragma unroll
    for (int i = 0; i < 2; ++i)
#pragma unroll
        for (int j = 0; j < 2; ++j)
#pragma unroll
            for (int r = 0; r < 4; ++r) acc[i][j][r] = 0.f;

    const int mh = (wave >> 1) * 32;
    const int nh = (wave & 1) * 32;
    const int lm = lane & 15;
    const int l8 = (lane >> 4) * 8;

    uint4 aReg, bReg;
    if (a_ok) aReg = *(const uint4*)(Abase + k0);
    else { aReg.x = aReg.y = aReg.z = aReg.w = 0u; }
    bReg = *(const uint4*)(Bbase + k0);

    for (int kt = k0; kt < k0 + Ks; kt += 32) {
        *(uint4*)&As[s_r][s_k8] = aReg;
        *(uint4*)&Bs[s_r][s_k8] = bReg;
        __syncthreads();

        if (kt + 32 < k0 + Ks) {
            if (a_ok) aReg = *(const uint4*)(Abase + kt + 32);
            bReg = *(const uint4*)(Bbase + kt + 32);
        }

        bf16x8 a0 = __builtin_bit_cast(bf16x8, *(const uint4*)&As[mh + lm][l8]);
        bf16x8 a1 = __builtin_bit_cast(bf16x8, *(const uint4*)&As[mh + 16 + lm][l8]);
        bf16x8 b0 = __builtin_bit_cast(bf16x8, *(const uint4*)&Bs[nh + lm][l8]);
        bf16x8 b1 = __builtin_bit_cast(bf16x8, *(const uint4*)&Bs[nh + 16 + lm][l8]);

        acc[0][0] = __builtin_amdgcn_mfma_f32_16x16x32_bf16(a0, b0, acc[0][0], 0, 0, 0);
        acc[0][1] = __builtin_amdgcn_mfma_f32_16x16x32_bf16(a0, b1, acc[0][1], 0, 0, 0);
        acc[1][0] = __builtin_amdgcn_mfma_f32_16x16x32_bf16(a1, b0, acc[1][0], 0, 0, 0);
        acc[1][1] = __builtin_amdgcn_mfma_f32_16x16x32_bf16(a1, b1, acc[1][1], 0, 0, 0);
        __syncthreads();
    }

#pragma unroll
    for (int ms = 0; ms < 2; ++ms)
#pragma unroll
        for (int ns = 0; ns < 2; ++ns) {
            int n  = nbase + nh + ns * 16 + lm;
            int m0 = mbase + mh + ms * 16 + (lane >> 4) * 4;
            float* Pp = P + ((size_t)bz * NROIS + n) * Mpad + m0;
            *(f32x4*)Pp = acc[ms][ns];
        }
}

// fc1 WITHOUT split-K: full K=512, fused bias+relu+bf16 epilogue.
__global__ __launch_bounds__(256) void fc1_fused(
    const unsigned short* __restrict__ Wb,
    const unsigned short* __restrict__ Act,
    const float* __restrict__ bias,
    unsigned short* __restrict__ outb)
{
    __shared__ unsigned short As[64][40];
    __shared__ unsigned short Bs[64][40];
    const int tid  = threadIdx.x;
    const int lane = tid & 63;
    const int wave = tid >> 6;
    const int mbase = blockIdx.x * 64;
    const int nbase = blockIdx.y * 64;

    const int s_r  = tid >> 2;
    const int s_k8 = (tid & 3) << 3;
    const unsigned short* Abase = Wb + (size_t)(mbase + s_r) * 512 + s_k8;
    const unsigned short* Bbase = Act + (size_t)(nbase + s_r) * 512 + s_k8;

    f32x4 acc[2][2];
#pragma unroll
    for (int i = 0; i < 2; ++i)
#pragma unroll
        for (int j = 0; j < 2; ++j)
#pragma unroll
            for (int r = 0; r < 4; ++r) acc[i][j][r] = 0.f;

    const int mh = (wave >> 1) * 32;
    const int nh = (wave & 1) * 32;
    const int lm = lane & 15;
    const int l8 = (lane >> 4) * 8;

    uint4 aReg = *(const uint4*)(Abase);
    uint4 bReg = *(const uint4*)(Bbase);

    for (int kt = 0; kt < 512; kt += 32) {
        *(uint4*)&As[s_r][s_k8] = aReg;
        *(uint4*)&Bs[s_r][s_k8] = bReg;
        __syncthreads();

        if (kt + 32 < 512) {
            aReg = *(const uint4*)(Abase + kt + 32);
            bReg = *(const uint4*)(Bbase + kt + 32);
        }

        bf16x8 a0 = __builtin_bit_cast(bf16x8, *(const uint4*)&As[mh + lm][l8]);
        bf16x8 a1 = __builtin_bit_cast(bf16x8, *(const uint4*)&As[mh + 16 + lm][l8]);
        bf16x8 b0 = __builtin_bit_cast(bf16x8, *(const uint4*)&Bs[nh + lm][l8]);
        bf16x8 b1 = __builtin_bit_cast(bf16x8, *(const uint4*)&Bs[nh + 16 + lm][l8]);

        acc[0][0] = __builtin_amdgcn_mfma_f32_16x16x32_bf16(a0, b0, acc[0][0], 0, 0, 0);
        acc[0][1] = __builtin_amdgcn_mfma_f32_16x16x32_bf16(a0, b1, acc[0][1], 0, 0, 0);
        acc[1][0] = __builtin_amdgcn_mfma_f32_16x16x32_bf16(a1, b0, acc[1][0], 0, 0, 0);
        acc[1][1] = __builtin_amdgcn_mfma_f32_16x16x32_bf16(a1, b1, acc[1][1], 0, 0, 0);
        __syncthreads();
    }

#pragma unroll
    for (int ms = 0; ms < 2; ++ms)
#pragma unroll
        for (int ns = 0; ns < 2; ++ns) {
            int n  = nbase + nh + ns * 16 + lm;
            int m0 = mbase + mh + ms * 16 + (lane >> 4) * 4;
            ushort4 v;
#pragma unroll
            for (int r = 0; r < 4; ++r) {
                float s = acc[ms][ns][r] + bias[m0 + r];
                s = fmaxf(s, 0.f);
                ((unsigned short*)&v)[r] = f2b(s);
            }
            *(ushort4*)(outb + (size_t)n * 2048 + m0) = v;
        }
}

// loc (192 blocks: 6x8x4) + score (128 blocks: 2x8x8) in one dispatch
__global__ __launch_bounds__(256) void fc_mfma_dual(
    const unsigned short* __restrict__ Wloc,
    const unsigned short* __restrict__ Wscore,
    const unsigned short* __restrict__ Act,
    float* __restrict__ Ploc, float* __restrict__ Pscore)
{
    __shared__ unsigned short As[64][40];
    __shared__ unsigned short Bs[64][40];
    int id = blockIdx.x;
    if (id < 192) {
        int bx = id % 6, by = (id / 6) % 8, bz = id / 48;
        fc_body(Wloc, Act, Ploc, 324, 2048, 384, 4, bx, by, bz, As, Bs);
    } else {
        int l = id - 192;
        int bx = l % 2, by = (l / 2) % 8, bz = l / 16;
        fc_body(Wscore, Act, Pscore, 81, 2048, 128, 8, bx, by, bz, As, Bs);
    }
}

// loc (648 blocks) + score (162 blocks) reduce in one dispatch
__global__ void fc_reduce_dual(
    const float* __restrict__ Ploc, const float* __restrict__ Pscore,
    const float* __restrict__ b_loc, const float* __restrict__ b_score,
    float* __restrict__ outLoc, float* __restrict__ outScore)
{
    int b = blockIdx.x;
    if (b < 648) {
        int idx = b * 256 + threadIdx.x;
        if (idx >= NROIS * 324) return;
        int n = idx / 324, m = idx - n * 324;
        float s = b_loc[m];
        for (int sp = 0; sp < 4; ++sp)
            s += Ploc[((size_t)sp * NROIS + n) * 384 + m];
        outLoc[idx] = s;
    } else {
        int idx = (b - 648) * 256 + threadIdx.x;
        if (idx >= NROIS * 81) return;
        int n = idx / 81, m = idx - n * 81;
        float s = b_score[m];
        for (int sp = 0; sp < 8; ++sp)
            s += Pscore[((size_t)sp * NROIS + n) * 128 + m];
        outScore[idx] = s;
    }
}

extern "C" void kernel_launch(void* const* d_in, const int* in_sizes, int n_in,
                              void* d_out, int out_size, void* d_ws, size_t ws_size,
                              hipStream_t stream) {
    const float* x         = (const float*)d_in[0];
    const float* rois      = (const float*)d_in[1];
    const float* w_col_max = (const float*)d_in[2];
    const float* b_col_max = (const float*)d_in[3];
    const float* w_col     = (const float*)d_in[4];
    const float* b_col     = (const float*)d_in[5];
    const float* w_row_max = (const float*)d_in[6];
    const float* b_row_max = (const float*)d_in[7];
    const float* w_row     = (const float*)d_in[8];
    const float* b_row     = (const float*)d_in[9];
    const float* w_fc1     = (const float*)d_in[10];
    const float* b_fc1     = (const float*)d_in[11];
    const float* w_score   = (const float*)d_in[12];
    const float* b_score   = (const float*)d_in[13];
    const float* w_loc     = (const float*)d_in[14];
    const float* b_loc     = (const float*)d_in[15];

    float* part0 = (float*)d_ws;                       // 7,782,400 f = 31.1 MB
    float* part1 = part0 + 7782400;                    // 7,782,400 f = 31.1 MB
    unsigned short* XvU   = (unsigned short*)(part1 + 7782400); // 5,427,264
    unsigned short* XhU   = XvU + 5427264;             // 5,058,624
    unsigned short* wbig0 = XhU + 5058624;             // 8,388,608 (col-max)
    unsigned short* wbig1 = wbig0 + 8388608;           // 8,388,608 (row-max)
    unsigned short* wc16  = wbig1 + 8388608;           // 2,007,040
    unsigned short* wr16  = wc16 + 2007040;            // 2,007,040
    unsigned short* c1colb= wr16 + 2007040;            //   632,384
    unsigned short* c1rowb= c1colb + 632384;           //   678,464
    unsigned short* wfc1b = c1rowb + 678464;           // 1,048,576
    unsigned short* pooledb = wfc1b + 1048576;         //   262,144
    unsigned short* fc1b  = pooledb + 262144;          // 1,048,576
    unsigned short* wlocb = fc1b + 1048576;            //   663,552
    unsigned short* wscoreb = wlocb + 663552;          //   165,888
    float* h = (float*)XhU;                            // alias (XhU dead after conv1)
    // total ~134 MB

    // ---- all prep in ONE dispatch ----
    prep_all<<<PREP_BLOCKS, 256, 0, stream>>>(
        x, w_col_max, w_row_max, w_col, w_row, w_fc1, w_loc, w_score,
        XvU, XhU, c1colb, wbig0, wbig1, wc16, wr16, wfc1b, wlocb, wscoreb);

    // ---- conv1 col(vertical)+row(horizontal) fused: 2 x 480 blocks ----
    conv_dual<<<960, 256, 0, stream>>>(
        wbig0, XvU, part0, CSV, 1, 53,
        wbig1, XhU, part1, CSH, 65, 1,
        256, 32768, 256, 15, 4, 1, 5, 480);
    reduce_pad_dual<<<950, 256, 0, stream>>>(
        part0, b_col_max, c1colb, CSH, 65, 1,
        part1, b_row_max, c1rowb, CSV, 1, 53,
        256, 16, 256, 475);

    // ---- conv2 col(horizontal)+row(vertical) fused ----
    conv_dual<<<960, 256, 0, stream>>>(
        wc16, c1colb, part0, CSH, 65, 1,
        wr16, c1rowb, part1, CSV, 1, 53,
        490, 4096, 512, 7, 3, 3, 5, 480);
    reduce_bias_dual<<<910, 256, 0, stream>>>(
        part0, part1, 512, 8, b_col, b_row, 490, h);

    // ---- PSROI pooling ----
    pool_kernel<<<512, 512, 0, stream>>>(h, rois, pooledb);

    float* out = (float*)d_out;
    // fc1: M=2048, K=512, NO split, fused bias+relu+bf16 epilogue
    fc1_fused<<<dim3(32, 8), 256, 0, stream>>>(wfc1b, pooledb, b_fc1, fc1b);

    // roi_cls_locs (M=324, split 4) + roi_scores (M=81, split 8) fused
    float* Ploc   = part0;                 // 4*512*384 = 786,432 f
    float* Pscore = part0 + 786432;        // 8*512*128 = 524,288 f
    fc_mfma_dual<<<320, 256, 0, stream>>>(wlocb, wscoreb, fc1b, Ploc, Pscore);
    fc_reduce_dual<<<810, 256, 0, stream>>>(Ploc, Pscore, b_loc, b_score,
                                            out, out + 512 * 324);
}

// Round 8
// 333.666 us; speedup vs baseline: 1.0571x; 1.0571x over previous
//
#include <hip/hip_runtime.h>
#include <math.h>

#define FW 50
#define FH 38
#define NPIX 1900   // 38*50
#define NROIS 512

// padded layouts
#define CSH 2470    // horizontal-consumed: [c][y*65 + x + t], width 65 = 50+15
#define CSV 2650    // vertical-consumed:   [c][x*53 + y + t], height 53 = 38+15

typedef __bf16 bf16x8 __attribute__((ext_vector_type(8)));
typedef float  f32x4  __attribute__((ext_vector_type(4)));
typedef float  f32x16 __attribute__((ext_vector_type(16)));

__device__ __forceinline__ unsigned short f2b(float f) {
    unsigned int u = __float_as_uint(f);
    unsigned int r = (u + 0x7fffu + ((u >> 16) & 1u)) >> 16;   // RNE
    return (unsigned short)r;
}

// ---------------------------------------------------------------------------
// prep_all: ALL preprocessing in ONE dispatch (launch overhead dominated).
// ---------------------------------------------------------------------------
#define PB0 21200            // xpad_v          : 2048*CSV elems
#define PB1 (PB0 + 19760)    // xpad_h          : 2048*CSH
#define PB2 (PB1 + 641)      // zero c1colb+row : 1,310,848 shorts / 8
#define PB3 (PB2 + 8192)     // repack big0     : 8,388,608 / 4
#define PB4 (PB3 + 8192)     // repack big1
#define PB5 (PB4 + 1960)     // repack wc16     : 2,007,040 / 4
#define PB6 (PB5 + 1960)     // repack wr16
#define PB7 (PB6 + 4096)     // cvt_pad fc1     : 2048*512
#define PB8 (PB7 + 648)      // cvt loc         : 663,552 / 4
#define PB9 (PB8 + 162)      // cvt score       : 165,888 / 4
#define PREP_BLOCKS PB9

__device__ __forceinline__ void repack4(
    const float* __restrict__ w, unsigned short* __restrict__ out,
    int gid, int n)
{
    int o = gid * 4;
    if (o >= n) return;
    int t0 = o & 15;
    int oc = o >> 4;
    ushort4 v;
    v.x = (t0     < 15) ? f2b(w[oc * 15 + t0    ]) : (unsigned short)0;
    v.y = (t0 + 1 < 15) ? f2b(w[oc * 15 + t0 + 1]) : (unsigned short)0;
    v.z = (t0 + 2 < 15) ? f2b(w[oc * 15 + t0 + 2]) : (unsigned short)0;
    v.w = (t0 + 3 < 15) ? f2b(w[oc * 15 + t0 + 3]) : (unsigned short)0;
    *(ushort4*)(out + o) = v;
}

__device__ __forceinline__ void cvt4(
    const float* __restrict__ in, unsigned short* __restrict__ out, int gid)
{
    int i = gid * 4;
    float4 v = *(const float4*)(in + i);
    ushort4 r;
    r.x = f2b(v.x); r.y = f2b(v.y); r.z = f2b(v.z); r.w = f2b(v.w);
    *(ushort4*)(out + i) = r;
}

__global__ __launch_bounds__(256) void prep_all(
    const float* __restrict__ x,
    const float* __restrict__ w_col_max, const float* __restrict__ w_row_max,
    const float* __restrict__ w_col,     const float* __restrict__ w_row,
    const float* __restrict__ w_fc1,
    const float* __restrict__ w_loc,     const float* __restrict__ w_score,
    unsigned short* __restrict__ XvU,    unsigned short* __restrict__ XhU,
    unsigned short* __restrict__ zeroDst,
    unsigned short* __restrict__ wbig0,  unsigned short* __restrict__ wbig1,
    unsigned short* __restrict__ wc16,   unsigned short* __restrict__ wr16,
    unsigned short* __restrict__ wfc1b,
    unsigned short* __restrict__ wlocb,  unsigned short* __restrict__ wscoreb)
{
    const int b = blockIdx.x;
    const int tid = threadIdx.x;
    if (b < PB0) {                                  // xpad_v
        int idx = b * 256 + tid;
        if (idx >= 2048 * CSV) return;
        int c = idx / CSV;
        int rem = idx - c * CSV;
        int xx = rem / 53;
        int yc = rem - xx * 53 - 7;
        unsigned short v = 0;
        if (yc >= 0 && yc < FH) v = f2b(x[(c * FH + yc) * FW + xx]);
        XvU[idx] = v;
    } else if (b < PB1) {                           // xpad_h
        int idx = (b - PB0) * 256 + tid;
        if (idx >= 2048 * CSH) return;
        int c = idx / CSH;
        int rem = idx - c * CSH;
        int y = rem / 65;
        int xc = rem - y * 65 - 7;
        unsigned short v = 0;
        if (xc >= 0 && xc < FW) v = f2b(x[(c * FH + y) * FW + xc]);
        XhU[idx] = v;
    } else if (b < PB2) {                           // zero pad buffers
        int i = ((b - PB1) * 256 + tid) * 8;
        if (i < 1310848) { uint4 z; z.x = z.y = z.z = z.w = 0u; *(uint4*)(zeroDst + i) = z; }
    } else if (b < PB3) {                           // repack w_col_max
        repack4(w_col_max, wbig0, (b - PB2) * 256 + tid, 8388608);
    } else if (b < PB4) {                           // repack w_row_max
        repack4(w_row_max, wbig1, (b - PB3) * 256 + tid, 8388608);
    } else if (b < PB5) {                           // repack w_col
        repack4(w_col, wc16, (b - PB4) * 256 + tid, 2007040);
    } else if (b < PB6) {                           // repack w_row
        repack4(w_row, wr16, (b - PB5) * 256 + tid, 2007040);
    } else if (b < PB7) {                           // cvt_pad w_fc1 (490 -> 512)
        int idx = (b - PB6) * 256 + tid;
        int rw = idx >> 9, k = idx & 511;
        wfc1b[idx] = (k < 490) ? f2b(w_fc1[(size_t)rw * 490 + k]) : (unsigned short)0;
    } else if (b < PB8) {                           // cvt w_loc
        cvt4(w_loc, wlocb, (b - PB7) * 256 + tid);
    } else {                                        // cvt w_score
        cvt4(w_score, wscoreb, (b - PB8) * 256 + tid);
    }
}

// ---------------------------------------------------------------------------
// DUAL tap-padded bf16 conv-as-GEMM, v8: R0-proven geometry (128x128 tile,
// 4 waves 2x2 of 64x64 32x32x16 MFMA, BK=32, [2][128][40] dbuf LDS, linear
// blockIdx) with a PHASE-SPLIT schedule:
//   per K-step: {reads kk0 + 4 MFMA} -> {stage next tile: alignbit+ds_write
//   to buf^1, issue t+2 prefetch} -> {reads kk1 + 4 MFMA} -> raw barrier
//   (lgkmcnt(0)+s_barrier, NO vmcnt drain).
// The staging is sandwiched BETWEEN MFMA clusters (compiler interleaves;
// matrix pipe starves only during sync+kk0-reads instead of the whole
// store+sync+read stretch). Raw barrier keeps the 2-deep register prefetch
// in flight across iterations (t+2 loads issued at t, consumed at t+1's
// stage with compiler-counted vmcnt). s_setprio(1) around MFMA clusters:
// waves now have role diversity (stage vs MFMA) for the arbiter.
// Race audit (1 barrier/iter): reads(buf,kk1)@t precede barrier(t);
// writes(buf)@t+1 follow it. writes(buf^1)@t vs reads(buf^1)@t-1 separated
// by barrier(t-1). Accumulation order unchanged (kk outer) -> bit-identical.
// C/D layout (32x32): col=lane&31, row=(reg&3)+8*(reg>>2)+4*(lane>>5).
// ---------------------------------------------------------------------------
__global__ __launch_bounds__(256) void conv_dual(
    const unsigned short* __restrict__ W0, const unsigned short* __restrict__ X0,
    float* __restrict__ P0, int CS0, int yMul0, int xMul0,
    const unsigned short* __restrict__ W1, const unsigned short* __restrict__ X1,
    float* __restrict__ P1, int CS1, int yMul1, int xMul1,
    int M, int Kp, int Mpad,
    int zMask, int zBits, int yMask, int xShift, int halfGrid)
{
    int id = blockIdx.x;
    const unsigned short* Wt; const unsigned short* Xp; float* P;
    int CS, yMul, xMul;
    if (id < halfGrid) {
        Wt = W0; Xp = X0; P = P0; CS = CS0; yMul = yMul0; xMul = xMul0;
    } else {
        id -= halfGrid;
        Wt = W1; Xp = X1; P = P1; CS = CS1; yMul = yMul1; xMul = xMul1;
    }
    const int zt = id & zMask;
    const int yt = (id >> zBits) & yMask;
    const int xt = id >> xShift;
    const int nsplit = zMask + 1;

    const int Ks = Kp / nsplit;
    const int k0 = zt * Ks;
    const int tid  = threadIdx.x;
    const int lane = tid & 63;
    const int wave = tid >> 6;
    const int mbase = yt * 128;
    const int pbase = xt * 128;

    __shared__ unsigned short As[2][128][40];
    __shared__ unsigned short Bt[2][128][40];

    // A staging: 128 rows x 32 k; thread: row=tid>>1, k-half=(tid&1)*16
    const int a_row = tid >> 1;
    const int a_k16 = (tid & 1) << 4;
    const int a_src = min(mbase + a_row, M - 1);   // clamp; dups land in Mpad pad
    const unsigned short* Abase = Wt + (size_t)a_src * Kp + a_k16;

    // B staging: 128 pixels x 32 k; thread: pixel=tid>>1, channel-half=tid&1
    const int b_pix = tid >> 1;
    const int bh    = tid & 1;
    int p = pbase + b_pix;
    if (p > NPIX - 1) p = NPIX - 1;          // clamp (stores guarded)
    const int py = p / FW, px = p - py * FW;
    const int pixBase = py * yMul + px * xMul;
    const unsigned* __restrict__ Bdw = (const unsigned*)Xp;

    f32x16 acc[2][2];
#pragma unroll
    for (int i = 0; i < 2; ++i)
#pragma unroll
        for (int j = 0; j < 2; ++j)
#pragma unroll
            for (int r = 0; r < 16; ++r) acc[i][j][r] = 0.f;

    const int wy = (wave >> 1) * 64;
    const int wx = (wave & 1) * 64;
    const int l5 = lane & 31;
    const int l8 = (lane >> 5) * 8;

    uint4 aR0, aR1;
    unsigned d[9];

    auto loadA = [&](int kt) {
        aR0 = *(const uint4*)(Abase + kt);
        aR1 = *(const uint4*)(Abase + kt + 8);
    };
    auto loadB = [&](int kt) {
        const int cg = (kt >> 4) + bh;               // this thread's channel
        const unsigned base = ((unsigned)(cg * CS + pixBase)) >> 1;
#pragma unroll
        for (int j = 0; j < 9; ++j) d[j] = Bdw[base + j];
    };

    loadA(k0); loadB(k0);
    const unsigned sh = ((unsigned)(pixBase & 1)) << 4;  // CS even -> parity fixed

    auto stage = [&](int bufw) {
        unsigned ob[8];
#pragma unroll
        for (int j = 0; j < 8; ++j)
            ob[j] = __builtin_amdgcn_alignbit(d[j + 1], d[j], sh);
        *(uint4*)&As[bufw][a_row][a_k16]     = aR0;
        *(uint4*)&As[bufw][a_row][a_k16 + 8] = aR1;
        *(uint4*)&Bt[bufw][b_pix][bh * 16]     = *(uint4*)&ob[0];
        *(uint4*)&Bt[bufw][b_pix][bh * 16 + 8] = *(uint4*)&ob[4];
    };

    // prologue: stage tile0 into buf0, issue tile1 loads, barrier
    stage(0);
    loadA(k0 + 32); loadB(k0 + 32);      // Ks >= 64 always (512/2048)
    asm volatile("s_waitcnt lgkmcnt(0)" ::: "memory");
    __builtin_amdgcn_sched_barrier(0);
    __builtin_amdgcn_s_barrier();
    __builtin_amdgcn_sched_barrier(0);

    int buf = 0;
    for (int kt = k0; kt < k0 + Ks; kt += 32) {
        const char* Ab = (const char*)As[buf];
        const char* Bb = (const char*)Bt[buf];
        // ---- phase 1: kk=0 ----
        bf16x8 a00 = __builtin_bit_cast(bf16x8, *(const uint4*)&As[buf][wy + l5][l8]);
        bf16x8 a10 = __builtin_bit_cast(bf16x8, *(const uint4*)&As[buf][wy + 32 + l5][l8]);
        bf16x8 b00 = __builtin_bit_cast(bf16x8, *(const uint4*)&Bt[buf][wx + l5][l8]);
        bf16x8 b10 = __builtin_bit_cast(bf16x8, *(const uint4*)&Bt[buf][wx + 32 + l5][l8]);
        __builtin_amdgcn_s_setprio(1);
        acc[0][0] = __builtin_amdgcn_mfma_f32_32x32x16_bf16(a00, b00, acc[0][0], 0, 0, 0);
        acc[0][1] = __builtin_amdgcn_mfma_f32_32x32x16_bf16(a00, b10, acc[0][1], 0, 0, 0);
        acc[1][0] = __builtin_amdgcn_mfma_f32_32x32x16_bf16(a10, b00, acc[1][0], 0, 0, 0);
        acc[1][1] = __builtin_amdgcn_mfma_f32_32x32x16_bf16(a10, b10, acc[1][1], 0, 0, 0);
        __builtin_amdgcn_s_setprio(0);
        // ---- stage tile t+1 (regs loaded last iter), issue t+2 loads ----
        if (kt + 32 < k0 + Ks) {
            stage(buf ^ 1);
            if (kt + 64 < k0 + Ks) { loadA(kt + 64); loadB(kt + 64); }
        }
        // ---- phase 2: kk=1 ----
        bf16x8 a01 = __builtin_bit_cast(bf16x8, *(const uint4*)&As[buf][wy + l5][16 + l8]);
        bf16x8 a11 = __builtin_bit_cast(bf16x8, *(const uint4*)&As[buf][wy + 32 + l5][16 + l8]);
        bf16x8 b01 = __builtin_bit_cast(bf16x8, *(const uint4*)&Bt[buf][wx + l5][16 + l8]);
        bf16x8 b11 = __builtin_bit_cast(bf16x8, *(const uint4*)&Bt[buf][wx + 32 + l5][16 + l8]);
        __builtin_amdgcn_s_setprio(1);
        acc[0][0] = __builtin_amdgcn_mfma_f32_32x32x16_bf16(a01, b01, acc[0][0], 0, 0, 0);
        acc[0][1] = __builtin_amdgcn_mfma_f32_32x32x16_bf16(a01, b11, acc[0][1], 0, 0, 0);
        acc[1][0] = __builtin_amdgcn_mfma_f32_32x32x16_bf16(a11, b01, acc[1][0], 0, 0, 0);
        acc[1][1] = __builtin_amdgcn_mfma_f32_32x32x16_bf16(a11, b11, acc[1][1], 0, 0, 0);
        __builtin_amdgcn_s_setprio(0);
        // ---- end-of-iter raw barrier (no vmcnt drain: prefetch stays live) ----
        asm volatile("s_waitcnt lgkmcnt(0)" ::: "memory");
        __builtin_amdgcn_sched_barrier(0);
        __builtin_amdgcn_s_barrier();
        __builtin_amdgcn_sched_barrier(0);
        buf ^= 1;
        (void)Ab; (void)Bb;
    }

    float* Pp = P + (size_t)zt * Mpad * NPIX;
#pragma unroll
    for (int i = 0; i < 2; ++i) {
        const int mb = mbase + wy + i * 32 + (lane >> 5) * 4;
#pragma unroll
        for (int j = 0; j < 2; ++j) {
            const int pp = pbase + wx + j * 32 + l5;
            if (pp < NPIX) {
#pragma unroll
                for (int r = 0; r < 16; ++r) {
                    const int m = mb + (r & 3) + 8 * (r >> 2);
                    Pp[(size_t)m * NPIX + pp] = acc[i][j][r];
                }
            }
        }
    }
}

// conv1 dual reduce: both paths' partials + bias -> bf16 padded layouts.
// 4 pixels per thread, float4 partial loads. halfGrid = 475 blocks per path.
__global__ void reduce_pad_dual(
    const float* __restrict__ P0, const float* __restrict__ bias0,
    unsigned short* __restrict__ out0, int CS0, int yM0, int xM0,
    const float* __restrict__ P1, const float* __restrict__ bias1,
    unsigned short* __restrict__ out1, int CS1, int yM1, int xM1,
    int Mpad, int nsplit, int M, int halfGrid)
{
    int b = blockIdx.x;
    const float* P; const float* bias; unsigned short* outb;
    int CS, yMul, xMul;
    if (b < halfGrid) { P = P0; bias = bias0; outb = out0; CS = CS0; yMul = yM0; xMul = xM0; }
    else { b -= halfGrid; P = P1; bias = bias1; outb = out1; CS = CS1; yMul = yM1; xMul = xM1; }
    int idx4 = b * 256 + threadIdx.x;
    if (idx4 >= M * 475) return;
    int o = idx4 / 475;
    int p = (idx4 - o * 475) * 4;
    float bv = bias[o];
    f32x4 s = {bv, bv, bv, bv};
    for (int sp = 0; sp < nsplit; ++sp)
        s += *(const f32x4*)&P[((size_t)sp * Mpad + o) * NPIX + p];
#pragma unroll
    for (int e = 0; e < 4; ++e) {
        int pe = p + e;
        int y = pe / FW, x = pe - y * FW;
        outb[(size_t)o * CS + y * yMul + x * xMul + 7] = f2b(s[e]);
    }
}

// conv2 dual reduce: h = relu(sum P0 + sum P1 + b_col + b_row), fp32 raster.
__global__ void reduce_bias_dual(
    const float* __restrict__ P0, const float* __restrict__ P1,
    int Mpad, int nsplit,
    const float* __restrict__ bias0, const float* __restrict__ bias1,
    int M, float* __restrict__ outf)
{
    int idx4 = blockIdx.x * 256 + threadIdx.x;
    if (idx4 >= M * 475) return;
    int o = idx4 / 475;
    int p = (idx4 - o * 475) * 4;
    float bv = bias0[o] + bias1[o];
    f32x4 s = {bv, bv, bv, bv};
    for (int sp = 0; sp < nsplit; ++sp) {
        s += *(const f32x4*)&P0[((size_t)sp * Mpad + o) * NPIX + p];
        s += *(const f32x4*)&P1[((size_t)sp * Mpad + o) * NPIX + p];
    }
#pragma unroll
    for (int e = 0; e < 4; ++e) s[e] = fmaxf(s[e], 0.f);
    *(f32x4*)&outf[(size_t)o * NPIX + p] = s;
}

// ---------------------------------------------------------------------------
// PSROI bilinear pooling (fp32 h) -> bf16 pooled [512][512] zero-padded
// ---------------------------------------------------------------------------
__global__ __launch_bounds__(512) void pool_kernel(
    const float* __restrict__ h, const float* __restrict__ rois,
    unsigned short* __restrict__ pooledb)
{
    int n = blockIdx.x;
    int k = threadIdx.x;
    if (k >= 490) {
        pooledb[(size_t)n * 512 + k] = 0;
        return;
    }
    float x1 = rois[n * 4 + 0], y1 = rois[n * 4 + 1];
    float x2 = rois[n * 4 + 2], y2 = rois[n * 4 + 3];
    float xmin = x1 * (1.f / 16.f) / 50.f;
    float ymin = y1 * (1.f / 16.f) / 38.f;
    float xmax = x2 * (1.f / 16.f) / 50.f;
    float ymax = y2 * (1.f / 16.f) / 38.f;
    float step_x = (xmax - xmin) / 7.f;
    float step_y = (ymax - ymin) / 7.f;
    int bin = k / 10;
    int bi = bin / 7, bj = bin - bi * 7;
    const float* ch = h + (size_t)k * NPIX;
    float m = -INFINITY;
#pragma unroll
    for (int sy = 0; sy < 2; ++sy) {
        float yv = (ymin + (float)(bi + sy) * step_y) * 37.f;
        float y0 = floorf(yv);
        float fy = yv - y0;
        int yi0 = min(max((int)y0, 0), 37);
        int yi1 = min(max((int)y0 + 1, 0), 37);
#pragma unroll
        for (int sx = 0; sx < 2; ++sx) {
            float xv = (xmin + (float)(bj + sx) * step_x) * 49.f;
            float x0 = floorf(xv);
            float fx = xv - x0;
            int xi0 = min(max((int)x0, 0), 49);
            int xi1 = min(max((int)x0 + 1, 0), 49);
            float v00 = ch[yi0 * FW + xi0], v01 = ch[yi0 * FW + xi1];
            float v10 = ch[yi1 * FW + xi0], v11 = ch[yi1 * FW + xi1];
            float top = v00 + (v01 - v00) * fx;
            float bot = v10 + (v11 - v10) * fx;
            float val = top + (bot - top) * fy;
            m = fmaxf(m, val);
        }
    }
    pooledb[(size_t)n * 512 + k] = f2b(m);
}

// ---------------------------------------------------------------------------
// bf16 MFMA NT GEMM (FC): A = weights [M][Kld], B = acts [512][Kld], split-K.
// ---------------------------------------------------------------------------
__device__ __forceinline__ void fc_body(
    const unsigned short* __restrict__ Wb,
    const unsigned short* __restrict__ Act,
    float* __restrict__ P, int M, int Kld, int Mpad, int nsplit,
    int bx, int by, int bz,
    unsigned short (*As)[40], unsigned short (*Bs)[40])
{
    const int Ks = Kld / nsplit;
    const int k0 = bz * Ks;
    const int tid  = threadIdx.x;
    const int lane = tid & 63;
    const int wave = tid >> 6;
    const int mbase = bx * 64;
    const int nbase = by * 64;

    const int s_r  = tid >> 2;
    const int s_k8 = (tid & 3) << 3;
    const int a_row = mbase + s_r;
    const bool a_ok = a_row < M;
    const unsigned short* Abase = Wb + (size_t)a_row * Kld + s_k8;
    const unsigned short* Bbase = Act + (size_t)(nbase + s_r) * Kld + s_k8;

    f32x4 acc[2][2];
#pragma unroll
    for (int i = 0; i < 2; ++i)
#pragma unroll
        for (int j = 0; j < 2; ++j)
#pragma unroll
            for (int r = 0; r < 4; ++r) acc[i][j][r] = 0.f;

    const int mh = (wave >> 1) * 32;
    const int nh = (wave & 1) * 32;
    const int lm = lane & 15;
    const int l8 = (lane >> 4) * 8;

    uint4 aReg, bReg;
    if (a_ok) aReg = *(const uint4*)(Abase + k0);
    else { aReg.x = aReg.y = aReg.z = aReg.w = 0u; }
    bReg = *(const uint4*)(Bbase + k0);

    for (int kt = k0; kt < k0 + Ks; kt += 32) {
        *(uint4*)&As[s_r][s_k8] = aReg;
        *(uint4*)&Bs[s_r][s_k8] = bReg;
        __syncthreads();

        if (kt + 32 < k0 + Ks) {
            if (a_ok) aReg = *(const uint4*)(Abase + kt + 32);
            bReg = *(const uint4*)(Bbase + kt + 32);
        }

        bf16x8 a0 = __builtin_bit_cast(bf16x8, *(const uint4*)&As[mh + lm][l8]);
        bf16x8 a1 = __builtin_bit_cast(bf16x8, *(const uint4*)&As[mh + 16 + lm][l8]);
        bf16x8 b0 = __builtin_bit_cast(bf16x8, *(const uint4*)&Bs[nh + lm][l8]);
        bf16x8 b1 = __builtin_bit_cast(bf16x8, *(const uint4*)&Bs[nh + 16 + lm][l8]);

        acc[0][0] = __builtin_amdgcn_mfma_f32_16x16x32_bf16(a0, b0, acc[0][0], 0, 0, 0);
        acc[0][1] = __builtin_amdgcn_mfma_f32_16x16x32_bf16(a0, b1, acc[0][1], 0, 0, 0);
        acc[1][0] = __builtin_amdgcn_mfma_f32_16x16x32_bf16(a1, b0, acc[1][0], 0, 0, 0);
        acc[1][1] = __builtin_amdgcn_mfma_f32_16x16x32_bf16(a1, b1, acc[1][1], 0, 0, 0);
        __syncthreads();
    }

#pragma unroll
    for (int ms = 0; ms < 2; ++ms)
#pragma unroll
        for (int ns = 0; ns < 2; ++ns) {
            int n  = nbase + nh + ns * 16 + lm;
            int m0 = mbase + mh + ms * 16 + (lane >> 4) * 4;
            float* Pp = P + ((size_t)bz * NROIS + n) * Mpad + m0;
            *(f32x4*)Pp = acc[ms][ns];
        }
}

// fc1 WITHOUT split-K: full K=512, fused bias+relu+bf16 epilogue.
__global__ __launch_bounds__(256) void fc1_fused(
    const unsigned short* __restrict__ Wb,
    const unsigned short* __restrict__ Act,
    const float* __restrict__ bias,
    unsigned short* __restrict__ outb)
{
    __shared__ unsigned short As[64][40];
    __shared__ unsigned short Bs[64][40];
    const int tid  = threadIdx.x;
    const int lane = tid & 63;
    const int wave = tid >> 6;
    const int mbase = blockIdx.x * 64;
    const int nbase = blockIdx.y * 64;

    const int s_r  = tid >> 2;
    const int s_k8 = (tid & 3) << 3;
    const unsigned short* Abase = Wb + (size_t)(mbase + s_r) * 512 + s_k8;
    const unsigned short* Bbase = Act + (size_t)(nbase + s_r) * 512 + s_k8;

    f32x4 acc[2][2];
#pragma unroll
    for (int i = 0; i < 2; ++i)
#pragma unroll
        for (int j = 0; j < 2; ++j)
#pragma unroll
            for (int r = 0; r < 4; ++r) acc[i][j][r] = 0.f;

    const int mh = (wave >> 1) * 32;
    const int nh = (wave & 1) * 32;
    const int lm = lane & 15;
    const int l8 = (lane >> 4) * 8;

    uint4 aReg = *(const uint4*)(Abase);
    uint4 bReg = *(const uint4*)(Bbase);

    for (int kt = 0; kt < 512; kt += 32) {
        *(uint4*)&As[s_r][s_k8] = aReg;
        *(uint4*)&Bs[s_r][s_k8] = bReg;
        __syncthreads();

        if (kt + 32 < 512) {
            aReg = *(const uint4*)(Abase + kt + 32);
            bReg = *(const uint4*)(Bbase + kt + 32);
        }

        bf16x8 a0 = __builtin_bit_cast(bf16x8, *(const uint4*)&As[mh + lm][l8]);
        bf16x8 a1 = __builtin_bit_cast(bf16x8, *(const uint4*)&As[mh + 16 + lm][l8]);
        bf16x8 b0 = __builtin_bit_cast(bf16x8, *(const uint4*)&Bs[nh + lm][l8]);
        bf16x8 b1 = __builtin_bit_cast(bf16x8, *(const uint4*)&Bs[nh + 16 + lm][l8]);

        acc[0][0] = __builtin_amdgcn_mfma_f32_16x16x32_bf16(a0, b0, acc[0][0], 0, 0, 0);
        acc[0][1] = __builtin_amdgcn_mfma_f32_16x16x32_bf16(a0, b1, acc[0][1], 0, 0, 0);
        acc[1][0] = __builtin_amdgcn_mfma_f32_16x16x32_bf16(a1, b0, acc[1][0], 0, 0, 0);
        acc[1][1] = __builtin_amdgcn_mfma_f32_16x16x32_bf16(a1, b1, acc[1][1], 0, 0, 0);
        __syncthreads();
    }

#pragma unroll
    for (int ms = 0; ms < 2; ++ms)
#pragma unroll
        for (int ns = 0; ns < 2; ++ns) {
            int n  = nbase + nh + ns * 16 + lm;
            int m0 = mbase + mh + ms * 16 + (lane >> 4) * 4;
            ushort4 v;
#pragma unroll
            for (int r = 0; r < 4; ++r) {
                float s = acc[ms][ns][r] + bias[m0 + r];
                s = fmaxf(s, 0.f);
                ((unsigned short*)&v)[r] = f2b(s);
            }
            *(ushort4*)(outb + (size_t)n * 2048 + m0) = v;
        }
}

// loc (192 blocks: 6x8x4) + score (128 blocks: 2x8x8) in one dispatch
__global__ __launch_bounds__(256) void fc_mfma_dual(
    const unsigned short* __restrict__ Wloc,
    const unsigned short* __restrict__ Wscore,
    const unsigned short* __restrict__ Act,
    float* __restrict__ Ploc, float* __restrict__ Pscore)
{
    __shared__ unsigned short As[64][40];
    __shared__ unsigned short Bs[64][40];
    int id = blockIdx.x;
    if (id < 192) {
        int bx = id % 6, by = (id / 6) % 8, bz = id / 48;
        fc_body(Wloc, Act, Ploc, 324, 2048, 384, 4, bx, by, bz, As, Bs);
    } else {
        int l = id - 192;
        int bx = l % 2, by = (l / 2) % 8, bz = l / 16;
        fc_body(Wscore, Act, Pscore, 81, 2048, 128, 8, bx, by, bz, As, Bs);
    }
}

// loc (648 blocks) + score (162 blocks) reduce in one dispatch
__global__ void fc_reduce_dual(
    const float* __restrict__ Ploc, const float* __restrict__ Pscore,
    const float* __restrict__ b_loc, const float* __restrict__ b_score,
    float* __restrict__ outLoc, float* __restrict__ outScore)
{
    int b = blockIdx.x;
    if (b < 648) {
        int idx = b * 256 + threadIdx.x;
        if (idx >= NROIS * 324) return;
        int n = idx / 324, m = idx - n * 324;
        float s = b_loc[m];
        for (int sp = 0; sp < 4; ++sp)
            s += Ploc[((size_t)sp * NROIS + n) * 384 + m];
        outLoc[idx] = s;
    } else {
        int idx = (b - 648) * 256 + threadIdx.x;
        if (idx >= NROIS * 81) return;
        int n = idx / 81, m = idx - n * 81;
        float s = b_score[m];
        for (int sp = 0; sp < 8; ++sp)
            s += Pscore[((size_t)sp * NROIS + n) * 128 + m];
        outScore[idx] = s;
    }
}

extern "C" void kernel_launch(void* const* d_in, const int* in_sizes, int n_in,
                              void* d_out, int out_size, void* d_ws, size_t ws_size,
                              hipStream_t stream) {
    const float* x         = (const float*)d_in[0];
    const float* rois      = (const float*)d_in[1];
    const float* w_col_max = (const float*)d_in[2];
    const float* b_col_max = (const float*)d_in[3];
    const float* w_col     = (const float*)d_in[4];
    const float* b_col     = (const float*)d_in[5];
    const float* w_row_max = (const float*)d_in[6];
    const float* b_row_max = (const float*)d_in[7];
    const float* w_row     = (const float*)d_in[8];
    const float* b_row     = (const float*)d_in[9];
    const float* w_fc1     = (const float*)d_in[10];
    const float* b_fc1     = (const float*)d_in[11];
    const float* w_score   = (const float*)d_in[12];
    const float* b_score   = (const float*)d_in[13];
    const float* w_loc     = (const float*)d_in[14];
    const float* b_loc     = (const float*)d_in[15];

    float* part0 = (float*)d_ws;                       // 7,782,400 f = 31.1 MB
    float* part1 = part0 + 7782400;                    // 7,782,400 f = 31.1 MB
    unsigned short* XvU   = (unsigned short*)(part1 + 7782400); // 5,427,264
    unsigned short* XhU   = XvU + 5427264;             // 5,058,624
    unsigned short* wbig0 = XhU + 5058624;             // 8,388,608 (col-max)
    unsigned short* wbig1 = wbig0 + 8388608;           // 8,388,608 (row-max)
    unsigned short* wc16  = wbig1 + 8388608;           // 2,007,040
    unsigned short* wr16  = wc16 + 2007040;            // 2,007,040
    unsigned short* c1colb= wr16 + 2007040;            //   632,384
    unsigned short* c1rowb= c1colb + 632384;           //   678,464
    unsigned short* wfc1b = c1rowb + 678464;           // 1,048,576
    unsigned short* pooledb = wfc1b + 1048576;         //   262,144
    unsigned short* fc1b  = pooledb + 262144;          // 1,048,576
    unsigned short* wlocb = fc1b + 1048576;            //   663,552
    unsigned short* wscoreb = wlocb + 663552;          //   165,888
    float* h = (float*)XhU;                            // alias (XhU dead after conv1)
    // total ~134 MB

    // ---- all prep in ONE dispatch ----
    prep_all<<<PREP_BLOCKS, 256, 0, stream>>>(
        x, w_col_max, w_row_max, w_col, w_row, w_fc1, w_loc, w_score,
        XvU, XhU, c1colb, wbig0, wbig1, wc16, wr16, wfc1b, wlocb, wscoreb);

    // ---- conv1 col(vertical)+row(horizontal) fused: 2 x 480 blocks ----
    conv_dual<<<960, 256, 0, stream>>>(
        wbig0, XvU, part0, CSV, 1, 53,
        wbig1, XhU, part1, CSH, 65, 1,
        256, 32768, 256, 15, 4, 1, 5, 480);
    reduce_pad_dual<<<950, 256, 0, stream>>>(
        part0, b_col_max, c1colb, CSH, 65, 1,
        part1, b_row_max, c1rowb, CSV, 1, 53,
        256, 16, 256, 475);

    // ---- conv2 col(horizontal)+row(vertical) fused ----
    conv_dual<<<960, 256, 0, stream>>>(
        wc16, c1colb, part0, CSH, 65, 1,
        wr16, c1rowb, part1, CSV, 1, 53,
        490, 4096, 512, 7, 3, 3, 5, 480);
    reduce_bias_dual<<<910, 256, 0, stream>>>(
        part0, part1, 512, 8, b_col, b_row, 490, h);

    // ---- PSROI pooling ----
    pool_kernel<<<512, 512, 0, stream>>>(h, rois, pooledb);

    float* out = (float*)d_out;
    // fc1: M=2048, K=512, NO split, fused bias+relu+bf16 epilogue
    fc1_fused<<<dim3(32, 8), 256, 0, stream>>>(wfc1b, pooledb, b_fc1, fc1b);

    // roi_cls_locs (M=324, split 4) + roi_scores (M=81, split 8) fused
    float* Ploc   = part0;                 // 4*512*384 = 786,432 f
    float* Pscore = part0 + 786432;        // 8*512*128 = 524,288 f
    fc_mfma_dual<<<320, 256, 0, stream>>>(wlocb, wscoreb, fc1b, Ploc, Pscore);
    fc_reduce_dual<<<810, 256, 0, stream>>>(Ploc, Pscore, b_loc, b_score,
                                            out, out + 512 * 324);
}

// Round 9
// 329.349 us; speedup vs baseline: 1.0710x; 1.0131x over previous
//
#include <hip/hip_runtime.h>
#include <math.h>

#define FW 50
#define FH 38
#define NPIX 1900   // 38*50
#define NROIS 512

// padded layouts
#define CSH 2470    // horizontal-consumed: [c][y*65 + x + t], width 65 = 50+15
#define CSV 2650    // vertical-consumed:   [c][x*53 + y + t], height 53 = 38+15

typedef __bf16 bf16x8 __attribute__((ext_vector_type(8)));
typedef float  f32x4  __attribute__((ext_vector_type(4)));
typedef float  f32x16 __attribute__((ext_vector_type(16)));

__device__ __forceinline__ unsigned short f2b(float f) {
    unsigned int u = __float_as_uint(f);
    unsigned int r = (u + 0x7fffu + ((u >> 16) & 1u)) >> 16;   // RNE
    return (unsigned short)r;
}

// ---------------------------------------------------------------------------
// prep_all: ALL preprocessing in ONE dispatch.
// v9: xpad segments do 4 outputs/thread (one decode per quad, incremental
// row-fix, ushort4 store) -- 41K blocks -> 10.2K for the pad segments.
// ---------------------------------------------------------------------------
#define PB0 5300             // xpad_v x4 : 2048*2650/4/256 (exact)
#define PB1 (PB0 + 4940)     // xpad_h x4 : 2048*2470/4/256 (exact)
#define PB2 (PB1 + 641)      // zero c1colb+row : 1,310,848 shorts / 8
#define PB3 (PB2 + 8192)     // repack big0     : 8,388,608 / 4
#define PB4 (PB3 + 8192)     // repack big1
#define PB5 (PB4 + 1960)     // repack wc16     : 2,007,040 / 4
#define PB6 (PB5 + 1960)     // repack wr16
#define PB7 (PB6 + 4096)     // cvt_pad fc1     : 2048*512
#define PB8 (PB7 + 648)      // cvt loc         : 663,552 / 4
#define PB9 (PB8 + 162)      // cvt score       : 165,888 / 4
#define PREP_BLOCKS PB9

__device__ __forceinline__ void repack4(
    const float* __restrict__ w, unsigned short* __restrict__ out,
    int gid, int n)
{
    int o = gid * 4;
    if (o >= n) return;
    int t0 = o & 15;
    int oc = o >> 4;
    ushort4 v;
    v.x = (t0     < 15) ? f2b(w[oc * 15 + t0    ]) : (unsigned short)0;
    v.y = (t0 + 1 < 15) ? f2b(w[oc * 15 + t0 + 1]) : (unsigned short)0;
    v.z = (t0 + 2 < 15) ? f2b(w[oc * 15 + t0 + 2]) : (unsigned short)0;
    v.w = (t0 + 3 < 15) ? f2b(w[oc * 15 + t0 + 3]) : (unsigned short)0;
    *(ushort4*)(out + o) = v;
}

__device__ __forceinline__ void cvt4(
    const float* __restrict__ in, unsigned short* __restrict__ out, int gid)
{
    int i = gid * 4;
    float4 v = *(const float4*)(in + i);
    ushort4 r;
    r.x = f2b(v.x); r.y = f2b(v.y); r.z = f2b(v.z); r.w = f2b(v.w);
    *(ushort4*)(out + i) = r;
}

__global__ __launch_bounds__(256) void prep_all(
    const float* __restrict__ x,
    const float* __restrict__ w_col_max, const float* __restrict__ w_row_max,
    const float* __restrict__ w_col,     const float* __restrict__ w_row,
    const float* __restrict__ w_fc1,
    const float* __restrict__ w_loc,     const float* __restrict__ w_score,
    unsigned short* __restrict__ XvU,    unsigned short* __restrict__ XhU,
    unsigned short* __restrict__ zeroDst,
    unsigned short* __restrict__ wbig0,  unsigned short* __restrict__ wbig1,
    unsigned short* __restrict__ wc16,   unsigned short* __restrict__ wr16,
    unsigned short* __restrict__ wfc1b,
    unsigned short* __restrict__ wlocb,  unsigned short* __restrict__ wscoreb)
{
    const int b = blockIdx.x;
    const int tid = threadIdx.x;
    if (b < PB0) {                                  // xpad_v, 4 outs/thread
        int o4 = (b * 256 + tid) * 4;               // < 5,427,200 exact
        int c = o4 / CSV;
        int rem = o4 - c * CSV;
        if (rem <= CSV - 4) {                       // quad within one channel
            int xx = rem / 53;
            int yl = rem - xx * 53;
            ushort4 v;
#pragma unroll
            for (int e = 0; e < 4; ++e) {
                int y2 = yl + e, x2 = xx;
                if (y2 >= 53) { y2 -= 53; x2 += 1; }
                int yc = y2 - 7;
                unsigned short val = 0;
                if (yc >= 0 && yc < FH) val = f2b(x[(c * FH + yc) * FW + x2]);
                ((unsigned short*)&v)[e] = val;
            }
            *(ushort4*)(XvU + o4) = v;              // o4 mult of 4 -> 8B aligned
        } else {                                    // rare channel-crossing quad
            for (int e = 0; e < 4; ++e) {
                int idx = o4 + e;
                int cc = idx / CSV; int r2 = idx - cc * CSV;
                int xx = r2 / 53; int yc = r2 - xx * 53 - 7;
                unsigned short val = 0;
                if (yc >= 0 && yc < FH) val = f2b(x[(cc * FH + yc) * FW + xx]);
                XvU[idx] = val;
            }
        }
    } else if (b < PB1) {                           // xpad_h, 4 outs/thread
        int o4 = ((b - PB0) * 256 + tid) * 4;       // < 5,058,560 exact
        int c = o4 / CSH;
        int rem = o4 - c * CSH;
        if (rem <= CSH - 4) {
            int y = rem / 65;
            int xl = rem - y * 65;
            ushort4 v;
#pragma unroll
            for (int e = 0; e < 4; ++e) {
                int x2 = xl + e, y2 = y;
                if (x2 >= 65) { x2 -= 65; y2 += 1; }
                int xc = x2 - 7;
                unsigned short val = 0;
                if (xc >= 0 && xc < FW) val = f2b(x[(c * FH + y2) * FW + xc]);
                ((unsigned short*)&v)[e] = val;
            }
            *(ushort4*)(XhU + o4) = v;
        } else {
            for (int e = 0; e < 4; ++e) {
                int idx = o4 + e;
                int cc = idx / CSH; int r2 = idx - cc * CSH;
                int y = r2 / 65; int xc = r2 - y * 65 - 7;
                unsigned short val = 0;
                if (xc >= 0 && xc < FW) val = f2b(x[(cc * FH + y) * FW + xc]);
                XhU[idx] = val;
            }
        }
    } else if (b < PB2) {                           // zero pad buffers
        int i = ((b - PB1) * 256 + tid) * 8;
        if (i < 1310848) { uint4 z; z.x = z.y = z.z = z.w = 0u; *(uint4*)(zeroDst + i) = z; }
    } else if (b < PB3) {                           // repack w_col_max
        repack4(w_col_max, wbig0, (b - PB2) * 256 + tid, 8388608);
    } else if (b < PB4) {                           // repack w_row_max
        repack4(w_row_max, wbig1, (b - PB3) * 256 + tid, 8388608);
    } else if (b < PB5) {                           // repack w_col
        repack4(w_col, wc16, (b - PB4) * 256 + tid, 2007040);
    } else if (b < PB6) {                           // repack w_row
        repack4(w_row, wr16, (b - PB5) * 256 + tid, 2007040);
    } else if (b < PB7) {                           // cvt_pad w_fc1 (490 -> 512)
        int idx = (b - PB6) * 256 + tid;
        int rw = idx >> 9, k = idx & 511;
        wfc1b[idx] = (k < 490) ? f2b(w_fc1[(size_t)rw * 490 + k]) : (unsigned short)0;
    } else if (b < PB8) {                           // cvt w_loc
        cvt4(w_loc, wlocb, (b - PB7) * 256 + tid);
    } else {                                        // cvt w_score
        cvt4(w_score, wscoreb, (b - PB8) * 256 + tid);
    }
}

// ---------------------------------------------------------------------------
// DUAL tap-padded bf16 conv-as-GEMM, v9: R8's phase-split refined to FOUR
// MFMA clusters per K-step with the stage split into halves between them:
//   P1 {kk0 reads, 2 MFMA} -> S1 {alignbit + B ds_write(buf^1) + loadB t+2}
//   -> P1b {2 MFMA} -> S2 {A ds_write(buf^1) + loadA t+2}
//   -> P2 {kk1 reads, 2 MFMA} -> P2b {2 MFMA} -> raw barrier (lgkmcnt only).
// Finer interleave smooths LDS/matrix overlap (m196/m201 pattern); the
// 2-phase R8 version measured +6% -- this extends the same mechanism.
// Buffer discipline identical to R8 (write buf^1 between barriers; one
// barrier/iter; prefetch never drained by the barrier). Per-accumulator
// operation order unchanged (kk0 then kk1) -> bit-identical output.
// C/D layout (32x32): col=lane&31, row=(reg&3)+8*(reg>>2)+4*(lane>>5).
// ---------------------------------------------------------------------------
__global__ __launch_bounds__(256) void conv_dual(
    const unsigned short* __restrict__ W0, const unsigned short* __restrict__ X0,
    float* __restrict__ P0, int CS0, int yMul0, int xMul0,
    const unsigned short* __restrict__ W1, const unsigned short* __restrict__ X1,
    float* __restrict__ P1, int CS1, int yMul1, int xMul1,
    int M, int Kp, int Mpad,
    int zMask, int zBits, int yMask, int xShift, int halfGrid)
{
    int id = blockIdx.x;
    const unsigned short* Wt; const unsigned short* Xp; float* P;
    int CS, yMul, xMul;
    if (id < halfGrid) {
        Wt = W0; Xp = X0; P = P0; CS = CS0; yMul = yMul0; xMul = xMul0;
    } else {
        id -= halfGrid;
        Wt = W1; Xp = X1; P = P1; CS = CS1; yMul = yMul1; xMul = xMul1;
    }
    const int zt = id & zMask;
    const int yt = (id >> zBits) & yMask;
    const int xt = id >> xShift;
    const int nsplit = zMask + 1;

    const int Ks = Kp / nsplit;
    const int k0 = zt * Ks;
    const int tid  = threadIdx.x;
    const int lane = tid & 63;
    const int wave = tid >> 6;
    const int mbase = yt * 128;
    const int pbase = xt * 128;

    __shared__ unsigned short As[2][128][40];
    __shared__ unsigned short Bt[2][128][40];

    // A staging: 128 rows x 32 k; thread: row=tid>>1, k-half=(tid&1)*16
    const int a_row = tid >> 1;
    const int a_k16 = (tid & 1) << 4;
    const int a_src = min(mbase + a_row, M - 1);   // clamp; dups land in Mpad pad
    const unsigned short* Abase = Wt + (size_t)a_src * Kp + a_k16;

    // B staging: 128 pixels x 32 k; thread: pixel=tid>>1, channel-half=tid&1
    const int b_pix = tid >> 1;
    const int bh    = tid & 1;
    int p = pbase + b_pix;
    if (p > NPIX - 1) p = NPIX - 1;          // clamp (stores guarded)
    const int py = p / FW, px = p - py * FW;
    const int pixBase = py * yMul + px * xMul;
    const unsigned* __restrict__ Bdw = (const unsigned*)Xp;

    f32x16 acc[2][2];
#pragma unroll
    for (int i = 0; i < 2; ++i)
#pragma unroll
        for (int j = 0; j < 2; ++j)
#pragma unroll
            for (int r = 0; r < 16; ++r) acc[i][j][r] = 0.f;

    const int wy = (wave >> 1) * 64;
    const int wx = (wave & 1) * 64;
    const int l5 = lane & 31;
    const int l8 = (lane >> 5) * 8;

    uint4 aR0, aR1;
    unsigned d[9];

    auto loadA = [&](int kt) {
        aR0 = *(const uint4*)(Abase + kt);
        aR1 = *(const uint4*)(Abase + kt + 8);
    };
    auto loadB = [&](int kt) {
        const int cg = (kt >> 4) + bh;               // this thread's channel
        const unsigned base = ((unsigned)(cg * CS + pixBase)) >> 1;
#pragma unroll
        for (int j = 0; j < 9; ++j) d[j] = Bdw[base + j];
    };

    loadA(k0); loadB(k0);
    const unsigned sh = ((unsigned)(pixBase & 1)) << 4;  // CS even -> parity fixed

    // prologue: stage tile0 into buf0, issue tile1 loads, barrier
    {
        unsigned ob[8];
#pragma unroll
        for (int j = 0; j < 8; ++j)
            ob[j] = __builtin_amdgcn_alignbit(d[j + 1], d[j], sh);
        *(uint4*)&As[0][a_row][a_k16]     = aR0;
        *(uint4*)&As[0][a_row][a_k16 + 8] = aR1;
        *(uint4*)&Bt[0][b_pix][bh * 16]     = *(uint4*)&ob[0];
        *(uint4*)&Bt[0][b_pix][bh * 16 + 8] = *(uint4*)&ob[4];
    }
    loadA(k0 + 32); loadB(k0 + 32);      // Ks >= 64 always
    asm volatile("s_waitcnt lgkmcnt(0)" ::: "memory");
    __builtin_amdgcn_sched_barrier(0);
    __builtin_amdgcn_s_barrier();
    __builtin_amdgcn_sched_barrier(0);

    int buf = 0;
    for (int kt = k0; kt < k0 + Ks; kt += 32) {
        const bool more = kt + 32 < k0 + Ks;
        const bool more2 = kt + 64 < k0 + Ks;
        // ---- P1: kk0 reads + first MFMA pair ----
        bf16x8 a00 = __builtin_bit_cast(bf16x8, *(const uint4*)&As[buf][wy + l5][l8]);
        bf16x8 a10 = __builtin_bit_cast(bf16x8, *(const uint4*)&As[buf][wy + 32 + l5][l8]);
        bf16x8 b00 = __builtin_bit_cast(bf16x8, *(const uint4*)&Bt[buf][wx + l5][l8]);
        bf16x8 b10 = __builtin_bit_cast(bf16x8, *(const uint4*)&Bt[buf][wx + 32 + l5][l8]);
        __builtin_amdgcn_s_setprio(1);
        acc[0][0] = __builtin_amdgcn_mfma_f32_32x32x16_bf16(a00, b00, acc[0][0], 0, 0, 0);
        acc[0][1] = __builtin_amdgcn_mfma_f32_32x32x16_bf16(a00, b10, acc[0][1], 0, 0, 0);
        __builtin_amdgcn_s_setprio(0);
        // ---- S1: B-half stage (regs from last iter) + issue B t+2 ----
        if (more) {
            unsigned ob[8];
#pragma unroll
            for (int j = 0; j < 8; ++j)
                ob[j] = __builtin_amdgcn_alignbit(d[j + 1], d[j], sh);
            *(uint4*)&Bt[buf ^ 1][b_pix][bh * 16]     = *(uint4*)&ob[0];
            *(uint4*)&Bt[buf ^ 1][b_pix][bh * 16 + 8] = *(uint4*)&ob[4];
            if (more2) loadB(kt + 64);
        }
        // ---- P1b: second MFMA pair ----
        __builtin_amdgcn_s_setprio(1);
        acc[1][0] = __builtin_amdgcn_mfma_f32_32x32x16_bf16(a10, b00, acc[1][0], 0, 0, 0);
        acc[1][1] = __builtin_amdgcn_mfma_f32_32x32x16_bf16(a10, b10, acc[1][1], 0, 0, 0);
        __builtin_amdgcn_s_setprio(0);
        // ---- S2: A-half stage + issue A t+2 ----
        if (more) {
            *(uint4*)&As[buf ^ 1][a_row][a_k16]     = aR0;
            *(uint4*)&As[buf ^ 1][a_row][a_k16 + 8] = aR1;
            if (more2) loadA(kt + 64);
        }
        // ---- P2: kk1 reads + third MFMA pair ----
        bf16x8 a01 = __builtin_bit_cast(bf16x8, *(const uint4*)&As[buf][wy + l5][16 + l8]);
        bf16x8 a11 = __builtin_bit_cast(bf16x8, *(const uint4*)&As[buf][wy + 32 + l5][16 + l8]);
        bf16x8 b01 = __builtin_bit_cast(bf16x8, *(const uint4*)&Bt[buf][wx + l5][16 + l8]);
        bf16x8 b11 = __builtin_bit_cast(bf16x8, *(const uint4*)&Bt[buf][wx + 32 + l5][16 + l8]);
        __builtin_amdgcn_s_setprio(1);
        acc[0][0] = __builtin_amdgcn_mfma_f32_32x32x16_bf16(a01, b01, acc[0][0], 0, 0, 0);
        acc[0][1] = __builtin_amdgcn_mfma_f32_32x32x16_bf16(a01, b11, acc[0][1], 0, 0, 0);
        __builtin_amdgcn_s_setprio(0);
        // ---- P2b: fourth MFMA pair ----
        __builtin_amdgcn_s_setprio(1);
        acc[1][0] = __builtin_amdgcn_mfma_f32_32x32x16_bf16(a11, b01, acc[1][0], 0, 0, 0);
        acc[1][1] = __builtin_amdgcn_mfma_f32_32x32x16_bf16(a11, b11, acc[1][1], 0, 0, 0);
        __builtin_amdgcn_s_setprio(0);
        // ---- end-of-iter raw barrier (no vmcnt drain) ----
        asm volatile("s_waitcnt lgkmcnt(0)" ::: "memory");
        __builtin_amdgcn_sched_barrier(0);
        __builtin_amdgcn_s_barrier();
        __builtin_amdgcn_sched_barrier(0);
        buf ^= 1;
    }

    float* Pp = P + (size_t)zt * Mpad * NPIX;
#pragma unroll
    for (int i = 0; i < 2; ++i) {
        const int mb = mbase + wy + i * 32 + (lane >> 5) * 4;
#pragma unroll
        for (int j = 0; j < 2; ++j) {
            const int pp = pbase + wx + j * 32 + l5;
            if (pp < NPIX) {
#pragma unroll
                for (int r = 0; r < 16; ++r) {
                    const int m = mb + (r & 3) + 8 * (r >> 2);
                    Pp[(size_t)m * NPIX + pp] = acc[i][j][r];
                }
            }
        }
    }
}

// conv1 dual reduce: both paths' partials + bias -> bf16 padded layouts.
// 4 pixels per thread, float4 partial loads. halfGrid = 475 blocks per path.
__global__ void reduce_pad_dual(
    const float* __restrict__ P0, const float* __restrict__ bias0,
    unsigned short* __restrict__ out0, int CS0, int yM0, int xM0,
    const float* __restrict__ P1, const float* __restrict__ bias1,
    unsigned short* __restrict__ out1, int CS1, int yM1, int xM1,
    int Mpad, int nsplit, int M, int halfGrid)
{
    int b = blockIdx.x;
    const float* P; const float* bias; unsigned short* outb;
    int CS, yMul, xMul;
    if (b < halfGrid) { P = P0; bias = bias0; outb = out0; CS = CS0; yMul = yM0; xMul = xM0; }
    else { b -= halfGrid; P = P1; bias = bias1; outb = out1; CS = CS1; yMul = yM1; xMul = xM1; }
    int idx4 = b * 256 + threadIdx.x;
    if (idx4 >= M * 475) return;
    int o = idx4 / 475;
    int p = (idx4 - o * 475) * 4;
    float bv = bias[o];
    f32x4 s = {bv, bv, bv, bv};
    for (int sp = 0; sp < nsplit; ++sp)
        s += *(const f32x4*)&P[((size_t)sp * Mpad + o) * NPIX + p];
#pragma unroll
    for (int e = 0; e < 4; ++e) {
        int pe = p + e;
        int y = pe / FW, x = pe - y * FW;
        outb[(size_t)o * CS + y * yMul + x * xMul + 7] = f2b(s[e]);
    }
}

// conv2 dual reduce: h = relu(sum P0 + sum P1 + b_col + b_row), fp32 raster.
__global__ void reduce_bias_dual(
    const float* __restrict__ P0, const float* __restrict__ P1,
    int Mpad, int nsplit,
    const float* __restrict__ bias0, const float* __restrict__ bias1,
    int M, float* __restrict__ outf)
{
    int idx4 = blockIdx.x * 256 + threadIdx.x;
    if (idx4 >= M * 475) return;
    int o = idx4 / 475;
    int p = (idx4 - o * 475) * 4;
    float bv = bias0[o] + bias1[o];
    f32x4 s = {bv, bv, bv, bv};
    for (int sp = 0; sp < nsplit; ++sp) {
        s += *(const f32x4*)&P0[((size_t)sp * Mpad + o) * NPIX + p];
        s += *(const f32x4*)&P1[((size_t)sp * Mpad + o) * NPIX + p];
    }
#pragma unroll
    for (int e = 0; e < 4; ++e) s[e] = fmaxf(s[e], 0.f);
    *(f32x4*)&outf[(size_t)o * NPIX + p] = s;
}

// ---------------------------------------------------------------------------
// PSROI bilinear pooling (fp32 h) -> bf16 pooled [512][512] zero-padded
// ---------------------------------------------------------------------------
__global__ __launch_bounds__(512) void pool_kernel(
    const float* __restrict__ h, const float* __restrict__ rois,
    unsigned short* __restrict__ pooledb)
{
    int n = blockIdx.x;
    int k = threadIdx.x;
    if (k >= 490) {
        pooledb[(size_t)n * 512 + k] = 0;
        return;
    }
    float x1 = rois[n * 4 + 0], y1 = rois[n * 4 + 1];
    float x2 = rois[n * 4 + 2], y2 = rois[n * 4 + 3];
    float xmin = x1 * (1.f / 16.f) / 50.f;
    float ymin = y1 * (1.f / 16.f) / 38.f;
    float xmax = x2 * (1.f / 16.f) / 50.f;
    float ymax = y2 * (1.f / 16.f) / 38.f;
    float step_x = (xmax - xmin) / 7.f;
    float step_y = (ymax - ymin) / 7.f;
    int bin = k / 10;
    int bi = bin / 7, bj = bin - bi * 7;
    const float* ch = h + (size_t)k * NPIX;
    float m = -INFINITY;
#pragma unroll
    for (int sy = 0; sy < 2; ++sy) {
        float yv = (ymin + (float)(bi + sy) * step_y) * 37.f;
        float y0 = floorf(yv);
        float fy = yv - y0;
        int yi0 = min(max((int)y0, 0), 37);
        int yi1 = min(max((int)y0 + 1, 0), 37);
#pragma unroll
        for (int sx = 0; sx < 2; ++sx) {
            float xv = (xmin + (float)(bj + sx) * step_x) * 49.f;
            float x0 = floorf(xv);
            float fx = xv - x0;
            int xi0 = min(max((int)x0, 0), 49);
            int xi1 = min(max((int)x0 + 1, 0), 49);
            float v00 = ch[yi0 * FW + xi0], v01 = ch[yi0 * FW + xi1];
            float v10 = ch[yi1 * FW + xi0], v11 = ch[yi1 * FW + xi1];
            float top = v00 + (v01 - v00) * fx;
            float bot = v10 + (v11 - v10) * fx;
            float val = top + (bot - top) * fy;
            m = fmaxf(m, val);
        }
    }
    pooledb[(size_t)n * 512 + k] = f2b(m);
}

// ---------------------------------------------------------------------------
// bf16 MFMA NT GEMM (FC): A = weights [M][Kld], B = acts [512][Kld], split-K.
// ---------------------------------------------------------------------------
__device__ __forceinline__ void fc_body(
    const unsigned short* __restrict__ Wb,
    const unsigned short* __restrict__ Act,
    float* __restrict__ P, int M, int Kld, int Mpad, int nsplit,
    int bx, int by, int bz,
    unsigned short (*As)[40], unsigned short (*Bs)[40])
{
    const int Ks = Kld / nsplit;
    const int k0 = bz * Ks;
    const int tid  = threadIdx.x;
    const int lane = tid & 63;
    const int wave = tid >> 6;
    const int mbase = bx * 64;
    const int nbase = by * 64;

    const int s_r  = tid >> 2;
    const int s_k8 = (tid & 3) << 3;
    const int a_row = mbase + s_r;
    const bool a_ok = a_row < M;
    const unsigned short* Abase = Wb + (size_t)a_row * Kld + s_k8;
    const unsigned short* Bbase = Act + (size_t)(nbase + s_r) * Kld + s_k8;

    f32x4 acc[2][2];
#pragma unroll
    for (int i = 0; i < 2; ++i)
#pragma unroll
        for (int j = 0; j < 2; ++j)
#pragma unroll
            for (int r = 0; r < 4; ++r) acc[i][j][r] = 0.f;

    const int mh = (wave >> 1) * 32;
    const int nh = (wave & 1) * 32;
    const int lm = lane & 15;
    const int l8 = (lane >> 4) * 8;

    uint4 aReg, bReg;
    if (a_ok) aReg = *(const uint4*)(Abase + k0);
    else { aReg.x = aReg.y = aReg.z = aReg.w = 0u; }
    bReg = *(const uint4*)(Bbase + k0);

    for (int kt = k0; kt < k0 + Ks; kt += 32) {
        *(uint4*)&As[s_r][s_k8] = aReg;
        *(uint4*)&Bs[s_r][s_k8] = bReg;
        __syncthreads();

        if (kt + 32 < k0 + Ks) {
            if (a_ok) aReg = *(const uint4*)(Abase + kt + 32);
            bReg = *(const uint4*)(Bbase + kt + 32);
        }

        bf16x8 a0 = __builtin_bit_cast(bf16x8, *(const uint4*)&As[mh + lm][l8]);
        bf16x8 a1 = __builtin_bit_cast(bf16x8, *(const uint4*)&As[mh + 16 + lm][l8]);
        bf16x8 b0 = __builtin_bit_cast(bf16x8, *(const uint4*)&Bs[nh + lm][l8]);
        bf16x8 b1 = __builtin_bit_cast(bf16x8, *(const uint4*)&Bs[nh + 16 + lm][l8]);

        acc[0][0] = __builtin_amdgcn_mfma_f32_16x16x32_bf16(a0, b0, acc[0][0], 0, 0, 0);
        acc[0][1] = __builtin_amdgcn_mfma_f32_16x16x32_bf16(a0, b1, acc[0][1], 0, 0, 0);
        acc[1][0] = __builtin_amdgcn_mfma_f32_16x16x32_bf16(a1, b0, acc[1][0], 0, 0, 0);
        acc[1][1] = __builtin_amdgcn_mfma_f32_16x16x32_bf16(a1, b1, acc[1][1], 0, 0, 0);
        __syncthreads();
    }

#pragma unroll
    for (int ms = 0; ms < 2; ++ms)
#pragma unroll
        for (int ns = 0; ns < 2; ++ns) {
            int n  = nbase + nh + ns * 16 + lm;
            int m0 = mbase + mh + ms * 16 + (lane >> 4) * 4;
            float* Pp = P + ((size_t)bz * NROIS + n) * Mpad + m0;
            *(f32x4*)Pp = acc[ms][ns];
        }
}

// fc1 WITHOUT split-K: full K=512, fused bias+relu+bf16 epilogue.
__global__ __launch_bounds__(256) void fc1_fused(
    const unsigned short* __restrict__ Wb,
    const unsigned short* __restrict__ Act,
    const float* __restrict__ bias,
    unsigned short* __restrict__ outb)
{
    __shared__ unsigned short As[64][40];
    __shared__ unsigned short Bs[64][40];
    const int tid  = threadIdx.x;
    const int lane = tid & 63;
    const int wave = tid >> 6;
    const int mbase = blockIdx.x * 64;
    const int nbase = blockIdx.y * 64;

    const int s_r  = tid >> 2;
    const int s_k8 = (tid & 3) << 3;
    const unsigned short* Abase = Wb + (size_t)(mbase + s_r) * 512 + s_k8;
    const unsigned short* Bbase = Act + (size_t)(nbase + s_r) * 512 + s_k8;

    f32x4 acc[2][2];
#pragma unroll
    for (int i = 0; i < 2; ++i)
#pragma unroll
        for (int j = 0; j < 2; ++j)
#pragma unroll
            for (int r = 0; r < 4; ++r) acc[i][j][r] = 0.f;

    const int mh = (wave >> 1) * 32;
    const int nh = (wave & 1) * 32;
    const int lm = lane & 15;
    const int l8 = (lane >> 4) * 8;

    uint4 aReg = *(const uint4*)(Abase);
    uint4 bReg = *(const uint4*)(Bbase);

    for (int kt = 0; kt < 512; kt += 32) {
        *(uint4*)&As[s_r][s_k8] = aReg;
        *(uint4*)&Bs[s_r][s_k8] = bReg;
        __syncthreads();

        if (kt + 32 < 512) {
            aReg = *(const uint4*)(Abase + kt + 32);
            bReg = *(const uint4*)(Bbase + kt + 32);
        }

        bf16x8 a0 = __builtin_bit_cast(bf16x8, *(const uint4*)&As[mh + lm][l8]);
        bf16x8 a1 = __builtin_bit_cast(bf16x8, *(const uint4*)&As[mh + 16 + lm][l8]);
        bf16x8 b0 = __builtin_bit_cast(bf16x8, *(const uint4*)&Bs[nh + lm][l8]);
        bf16x8 b1 = __builtin_bit_cast(bf16x8, *(const uint4*)&Bs[nh + 16 + lm][l8]);

        acc[0][0] = __builtin_amdgcn_mfma_f32_16x16x32_bf16(a0, b0, acc[0][0], 0, 0, 0);
        acc[0][1] = __builtin_amdgcn_mfma_f32_16x16x32_bf16(a0, b1, acc[0][1], 0, 0, 0);
        acc[1][0] = __builtin_amdgcn_mfma_f32_16x16x32_bf16(a1, b0, acc[1][0], 0, 0, 0);
        acc[1][1] = __builtin_amdgcn_mfma_f32_16x16x32_bf16(a1, b1, acc[1][1], 0, 0, 0);
        __syncthreads();
    }

#pragma unroll
    for (int ms = 0; ms < 2; ++ms)
#pragma unroll
        for (int ns = 0; ns < 2; ++ns) {
            int n  = nbase + nh + ns * 16 + lm;
            int m0 = mbase + mh + ms * 16 + (lane >> 4) * 4;
            ushort4 v;
#pragma unroll
            for (int r = 0; r < 4; ++r) {
                float s = acc[ms][ns][r] + bias[m0 + r];
                s = fmaxf(s, 0.f);
                ((unsigned short*)&v)[r] = f2b(s);
            }
            *(ushort4*)(outb + (size_t)n * 2048 + m0) = v;
        }
}

// loc (192 blocks: 6x8x4) + score (128 blocks: 2x8x8) in one dispatch
__global__ __launch_bounds__(256) void fc_mfma_dual(
    const unsigned short* __restrict__ Wloc,
    const unsigned short* __restrict__ Wscore,
    const unsigned short* __restrict__ Act,
    float* __restrict__ Ploc, float* __restrict__ Pscore)
{
    __shared__ unsigned short As[64][40];
    __shared__ unsigned short Bs[64][40];
    int id = blockIdx.x;
    if (id < 192) {
        int bx = id % 6, by = (id / 6) % 8, bz = id / 48;
        fc_body(Wloc, Act, Ploc, 324, 2048, 384, 4, bx, by, bz, As, Bs);
    } else {
        int l = id - 192;
        int bx = l % 2, by = (l / 2) % 8, bz = l / 16;
        fc_body(Wscore, Act, Pscore, 81, 2048, 128, 8, bx, by, bz, As, Bs);
    }
}

// loc (648 blocks) + score (162 blocks) reduce in one dispatch
__global__ void fc_reduce_dual(
    const float* __restrict__ Ploc, const float* __restrict__ Pscore,
    const float* __restrict__ b_loc, const float* __restrict__ b_score,
    float* __restrict__ outLoc, float* __restrict__ outScore)
{
    int b = blockIdx.x;
    if (b < 648) {
        int idx = b * 256 + threadIdx.x;
        if (idx >= NROIS * 324) return;
        int n = idx / 324, m = idx - n * 324;
        float s = b_loc[m];
        for (int sp = 0; sp < 4; ++sp)
            s += Ploc[((size_t)sp * NROIS + n) * 384 + m];
        outLoc[idx] = s;
    } else {
        int idx = (b - 648) * 256 + threadIdx.x;
        if (idx >= NROIS * 81) return;
        int n = idx / 81, m = idx - n * 81;
        float s = b_score[m];
        for (int sp = 0; sp < 8; ++sp)
            s += Pscore[((size_t)sp * NROIS + n) * 128 + m];
        outScore[idx] = s;
    }
}

extern "C" void kernel_launch(void* const* d_in, const int* in_sizes, int n_in,
                              void* d_out, int out_size, void* d_ws, size_t ws_size,
                              hipStream_t stream) {
    const float* x         = (const float*)d_in[0];
    const float* rois      = (const float*)d_in[1];
    const float* w_col_max = (const float*)d_in[2];
    const float* b_col_max = (const float*)d_in[3];
    const float* w_col     = (const float*)d_in[4];
    const float* b_col     = (const float*)d_in[5];
    const float* w_row_max = (const float*)d_in[6];
    const float* b_row_max = (const float*)d_in[7];
    const float* w_row     = (const float*)d_in[8];
    const float* b_row     = (const float*)d_in[9];
    const float* w_fc1     = (const float*)d_in[10];
    const float* b_fc1     = (const float*)d_in[11];
    const float* w_score   = (const float*)d_in[12];
    const float* b_score   = (const float*)d_in[13];
    const float* w_loc     = (const float*)d_in[14];
    const float* b_loc     = (const float*)d_in[15];

    float* part0 = (float*)d_ws;                       // 7,782,400 f = 31.1 MB
    float* part1 = part0 + 7782400;                    // 7,782,400 f = 31.1 MB
    unsigned short* XvU   = (unsigned short*)(part1 + 7782400); // 5,427,264
    unsigned short* XhU   = XvU + 5427264;             // 5,058,624
    unsigned short* wbig0 = XhU + 5058624;             // 8,388,608 (col-max)
    unsigned short* wbig1 = wbig0 + 8388608;           // 8,388,608 (row-max)
    unsigned short* wc16  = wbig1 + 8388608;           // 2,007,040
    unsigned short* wr16  = wc16 + 2007040;            // 2,007,040
    unsigned short* c1colb= wr16 + 2007040;            //   632,384
    unsigned short* c1rowb= c1colb + 632384;           //   678,464
    unsigned short* wfc1b = c1rowb + 678464;           // 1,048,576
    unsigned short* pooledb = wfc1b + 1048576;         //   262,144
    unsigned short* fc1b  = pooledb + 262144;          // 1,048,576
    unsigned short* wlocb = fc1b + 1048576;            //   663,552
    unsigned short* wscoreb = wlocb + 663552;          //   165,888
    float* h = (float*)XhU;                            // alias (XhU dead after conv1)
    // total ~134 MB

    // ---- all prep in ONE dispatch ----
    prep_all<<<PREP_BLOCKS, 256, 0, stream>>>(
        x, w_col_max, w_row_max, w_col, w_row, w_fc1, w_loc, w_score,
        XvU, XhU, c1colb, wbig0, wbig1, wc16, wr16, wfc1b, wlocb, wscoreb);

    // ---- conv1 col(vertical)+row(horizontal) fused: 2 x 480 blocks ----
    conv_dual<<<960, 256, 0, stream>>>(
        wbig0, XvU, part0, CSV, 1, 53,
        wbig1, XhU, part1, CSH, 65, 1,
        256, 32768, 256, 15, 4, 1, 5, 480);
    reduce_pad_dual<<<950, 256, 0, stream>>>(
        part0, b_col_max, c1colb, CSH, 65, 1,
        part1, b_row_max, c1rowb, CSV, 1, 53,
        256, 16, 256, 475);

    // ---- conv2 col(horizontal)+row(vertical) fused ----
    conv_dual<<<960, 256, 0, stream>>>(
        wc16, c1colb, part0, CSH, 65, 1,
        wr16, c1rowb, part1, CSV, 1, 53,
        490, 4096, 512, 7, 3, 3, 5, 480);
    reduce_bias_dual<<<910, 256, 0, stream>>>(
        part0, part1, 512, 8, b_col, b_row, 490, h);

    // ---- PSROI pooling ----
    pool_kernel<<<512, 512, 0, stream>>>(h, rois, pooledb);

    float* out = (float*)d_out;
    // fc1: M=2048, K=512, NO split, fused bias+relu+bf16 epilogue
    fc1_fused<<<dim3(32, 8), 256, 0, stream>>>(wfc1b, pooledb, b_fc1, fc1b);

    // roi_cls_locs (M=324, split 4) + roi_scores (M=81, split 8) fused
    float* Ploc   = part0;                 // 4*512*384 = 786,432 f
    float* Pscore = part0 + 786432;        // 8*512*128 = 524,288 f
    fc_mfma_dual<<<320, 256, 0, stream>>>(wlocb, wscoreb, fc1b, Ploc, Pscore);
    fc_reduce_dual<<<810, 256, 0, stream>>>(Ploc, Pscore, b_loc, b_score,
                                            out, out + 512 * 324);
}

// Round 10
// 327.582 us; speedup vs baseline: 1.0768x; 1.0054x over previous
//
#include <hip/hip_runtime.h>
#include <math.h>

#define FW 50
#define FH 38
#define NPIX 1900   // 38*50
#define NROIS 512

// padded layouts
#define CSH 2470    // horizontal-consumed: [c][y*65 + x + t], width 65 = 50+15
#define CSV 2650    // vertical-consumed:   [c][x*53 + y + t], height 53 = 38+15

typedef __bf16 bf16x8 __attribute__((ext_vector_type(8)));
typedef float  f32x4  __attribute__((ext_vector_type(4)));
typedef float  f32x16 __attribute__((ext_vector_type(16)));

__device__ __forceinline__ unsigned short f2b(float f) {
    unsigned int u = __float_as_uint(f);
    unsigned int r = (u + 0x7fffu + ((u >> 16) & 1u)) >> 16;   // RNE
    return (unsigned short)r;
}

// ---------------------------------------------------------------------------
// prep_all: ALL preprocessing in ONE dispatch (R9-proven: xpad segments do
// 4 outputs/thread with one decode per quad + ushort4 store).
// ---------------------------------------------------------------------------
#define PB0 5300             // xpad_v x4 : 2048*2650/4/256 (exact)
#define PB1 (PB0 + 4940)     // xpad_h x4 : 2048*2470/4/256 (exact)
#define PB2 (PB1 + 641)      // zero c1colb+row : 1,310,848 shorts / 8
#define PB3 (PB2 + 8192)     // repack big0     : 8,388,608 / 4
#define PB4 (PB3 + 8192)     // repack big1
#define PB5 (PB4 + 1960)     // repack wc16     : 2,007,040 / 4
#define PB6 (PB5 + 1960)     // repack wr16
#define PB7 (PB6 + 4096)     // cvt_pad fc1     : 2048*512
#define PB8 (PB7 + 648)      // cvt loc         : 663,552 / 4
#define PB9 (PB8 + 162)      // cvt score       : 165,888 / 4
#define PREP_BLOCKS PB9

__device__ __forceinline__ void repack4(
    const float* __restrict__ w, unsigned short* __restrict__ out,
    int gid, int n)
{
    int o = gid * 4;
    if (o >= n) return;
    int t0 = o & 15;
    int oc = o >> 4;
    ushort4 v;
    v.x = (t0     < 15) ? f2b(w[oc * 15 + t0    ]) : (unsigned short)0;
    v.y = (t0 + 1 < 15) ? f2b(w[oc * 15 + t0 + 1]) : (unsigned short)0;
    v.z = (t0 + 2 < 15) ? f2b(w[oc * 15 + t0 + 2]) : (unsigned short)0;
    v.w = (t0 + 3 < 15) ? f2b(w[oc * 15 + t0 + 3]) : (unsigned short)0;
    *(ushort4*)(out + o) = v;
}

__device__ __forceinline__ void cvt4(
    const float* __restrict__ in, unsigned short* __restrict__ out, int gid)
{
    int i = gid * 4;
    float4 v = *(const float4*)(in + i);
    ushort4 r;
    r.x = f2b(v.x); r.y = f2b(v.y); r.z = f2b(v.z); r.w = f2b(v.w);
    *(ushort4*)(out + i) = r;
}

__global__ __launch_bounds__(256) void prep_all(
    const float* __restrict__ x,
    const float* __restrict__ w_col_max, const float* __restrict__ w_row_max,
    const float* __restrict__ w_col,     const float* __restrict__ w_row,
    const float* __restrict__ w_fc1,
    const float* __restrict__ w_loc,     const float* __restrict__ w_score,
    unsigned short* __restrict__ XvU,    unsigned short* __restrict__ XhU,
    unsigned short* __restrict__ zeroDst,
    unsigned short* __restrict__ wbig0,  unsigned short* __restrict__ wbig1,
    unsigned short* __restrict__ wc16,   unsigned short* __restrict__ wr16,
    unsigned short* __restrict__ wfc1b,
    unsigned short* __restrict__ wlocb,  unsigned short* __restrict__ wscoreb)
{
    const int b = blockIdx.x;
    const int tid = threadIdx.x;
    if (b < PB0) {                                  // xpad_v, 4 outs/thread
        int o4 = (b * 256 + tid) * 4;               // < 5,427,200 exact
        int c = o4 / CSV;
        int rem = o4 - c * CSV;
        if (rem <= CSV - 4) {                       // quad within one channel
            int xx = rem / 53;
            int yl = rem - xx * 53;
            ushort4 v;
#pragma unroll
            for (int e = 0; e < 4; ++e) {
                int y2 = yl + e, x2 = xx;
                if (y2 >= 53) { y2 -= 53; x2 += 1; }
                int yc = y2 - 7;
                unsigned short val = 0;
                if (yc >= 0 && yc < FH) val = f2b(x[(c * FH + yc) * FW + x2]);
                ((unsigned short*)&v)[e] = val;
            }
            *(ushort4*)(XvU + o4) = v;              // o4 mult of 4 -> 8B aligned
        } else {                                    // rare channel-crossing quad
            for (int e = 0; e < 4; ++e) {
                int idx = o4 + e;
                int cc = idx / CSV; int r2 = idx - cc * CSV;
                int xx = r2 / 53; int yc = r2 - xx * 53 - 7;
                unsigned short val = 0;
                if (yc >= 0 && yc < FH) val = f2b(x[(cc * FH + yc) * FW + xx]);
                XvU[idx] = val;
            }
        }
    } else if (b < PB1) {                           // xpad_h, 4 outs/thread
        int o4 = ((b - PB0) * 256 + tid) * 4;       // < 5,058,560 exact
        int c = o4 / CSH;
        int rem = o4 - c * CSH;
        if (rem <= CSH - 4) {
            int y = rem / 65;
            int xl = rem - y * 65;
            ushort4 v;
#pragma unroll
            for (int e = 0; e < 4; ++e) {
                int x2 = xl + e, y2 = y;
                if (x2 >= 65) { x2 -= 65; y2 += 1; }
                int xc = x2 - 7;
                unsigned short val = 0;
                if (xc >= 0 && xc < FW) val = f2b(x[(c * FH + y2) * FW + xc]);
                ((unsigned short*)&v)[e] = val;
            }
            *(ushort4*)(XhU + o4) = v;
        } else {
            for (int e = 0; e < 4; ++e) {
                int idx = o4 + e;
                int cc = idx / CSH; int r2 = idx - cc * CSH;
                int y = r2 / 65; int xc = r2 - y * 65 - 7;
                unsigned short val = 0;
                if (xc >= 0 && xc < FW) val = f2b(x[(cc * FH + y) * FW + xc]);
                XhU[idx] = val;
            }
        }
    } else if (b < PB2) {                           // zero pad buffers
        int i = ((b - PB1) * 256 + tid) * 8;
        if (i < 1310848) { uint4 z; z.x = z.y = z.z = z.w = 0u; *(uint4*)(zeroDst + i) = z; }
    } else if (b < PB3) {                           // repack w_col_max
        repack4(w_col_max, wbig0, (b - PB2) * 256 + tid, 8388608);
    } else if (b < PB4) {                           // repack w_row_max
        repack4(w_row_max, wbig1, (b - PB3) * 256 + tid, 8388608);
    } else if (b < PB5) {                           // repack w_col
        repack4(w_col, wc16, (b - PB4) * 256 + tid, 2007040);
    } else if (b < PB6) {                           // repack w_row
        repack4(w_row, wr16, (b - PB5) * 256 + tid, 2007040);
    } else if (b < PB7) {                           // cvt_pad w_fc1 (490 -> 512)
        int idx = (b - PB6) * 256 + tid;
        int rw = idx >> 9, k = idx & 511;
        wfc1b[idx] = (k < 490) ? f2b(w_fc1[(size_t)rw * 490 + k]) : (unsigned short)0;
    } else if (b < PB8) {                           // cvt w_loc
        cvt4(w_loc, wlocb, (b - PB7) * 256 + tid);
    } else {                                        // cvt w_score
        cvt4(w_score, wscoreb, (b - PB8) * 256 + tid);
    }
}

// ---------------------------------------------------------------------------
// DUAL tap-padded bf16 conv-as-GEMM — R8-PROVEN BODY (89.3 us, best measured).
// 128x128 block tile, 4 waves 2x2 of 64x64 (32x32x16 MFMA), BK=32,
// [2][128][40] dbuf LDS, linear blockIdx. TWO-phase split per K-step:
//   {kk0 reads + 4 MFMA} -> {stage next tile to buf^1 + issue t+2 prefetch}
//   -> {kk1 reads + 4 MFMA} -> raw barrier (lgkmcnt(0)+s_barrier, NO vmcnt
//   drain -- prefetch stays in flight across the barrier).
// R9's finer 4-phase split regressed (91.0 us): 2-phase is the optimal
// interleave granularity for this geometry.
// Race audit (1 barrier/iter): reads(buf,kk1)@t precede barrier(t);
// writes(buf)@t+1 follow it. writes(buf^1)@t vs reads(buf^1)@t-1 separated
// by barrier(t-1). Accumulation order unchanged -> bit-identical.
// C/D layout (32x32): col=lane&31, row=(reg&3)+8*(reg>>2)+4*(lane>>5).
// ---------------------------------------------------------------------------
__global__ __launch_bounds__(256) void conv_dual(
    const unsigned short* __restrict__ W0, const unsigned short* __restrict__ X0,
    float* __restrict__ P0, int CS0, int yMul0, int xMul0,
    const unsigned short* __restrict__ W1, const unsigned short* __restrict__ X1,
    float* __restrict__ P1, int CS1, int yMul1, int xMul1,
    int M, int Kp, int Mpad,
    int zMask, int zBits, int yMask, int xShift, int halfGrid)
{
    int id = blockIdx.x;
    const unsigned short* Wt; const unsigned short* Xp; float* P;
    int CS, yMul, xMul;
    if (id < halfGrid) {
        Wt = W0; Xp = X0; P = P0; CS = CS0; yMul = yMul0; xMul = xMul0;
    } else {
        id -= halfGrid;
        Wt = W1; Xp = X1; P = P1; CS = CS1; yMul = yMul1; xMul = xMul1;
    }
    const int zt = id & zMask;
    const int yt = (id >> zBits) & yMask;
    const int xt = id >> xShift;
    const int nsplit = zMask + 1;

    const int Ks = Kp / nsplit;
    const int k0 = zt * Ks;
    const int tid  = threadIdx.x;
    const int lane = tid & 63;
    const int wave = tid >> 6;
    const int mbase = yt * 128;
    const int pbase = xt * 128;

    __shared__ unsigned short As[2][128][40];
    __shared__ unsigned short Bt[2][128][40];

    // A staging: 128 rows x 32 k; thread: row=tid>>1, k-half=(tid&1)*16
    const int a_row = tid >> 1;
    const int a_k16 = (tid & 1) << 4;
    const int a_src = min(mbase + a_row, M - 1);   // clamp; dups land in Mpad pad
    const unsigned short* Abase = Wt + (size_t)a_src * Kp + a_k16;

    // B staging: 128 pixels x 32 k; thread: pixel=tid>>1, channel-half=tid&1
    const int b_pix = tid >> 1;
    const int bh    = tid & 1;
    int p = pbase + b_pix;
    if (p > NPIX - 1) p = NPIX - 1;          // clamp (stores guarded)
    const int py = p / FW, px = p - py * FW;
    const int pixBase = py * yMul + px * xMul;
    const unsigned* __restrict__ Bdw = (const unsigned*)Xp;

    f32x16 acc[2][2];
#pragma unroll
    for (int i = 0; i < 2; ++i)
#pragma unroll
        for (int j = 0; j < 2; ++j)
#pragma unroll
            for (int r = 0; r < 16; ++r) acc[i][j][r] = 0.f;

    const int wy = (wave >> 1) * 64;
    const int wx = (wave & 1) * 64;
    const int l5 = lane & 31;
    const int l8 = (lane >> 5) * 8;

    uint4 aR0, aR1;
    unsigned d[9];

    auto loadA = [&](int kt) {
        aR0 = *(const uint4*)(Abase + kt);
        aR1 = *(const uint4*)(Abase + kt + 8);
    };
    auto loadB = [&](int kt) {
        const int cg = (kt >> 4) + bh;               // this thread's channel
        const unsigned base = ((unsigned)(cg * CS + pixBase)) >> 1;
#pragma unroll
        for (int j = 0; j < 9; ++j) d[j] = Bdw[base + j];
    };

    loadA(k0); loadB(k0);
    const unsigned sh = ((unsigned)(pixBase & 1)) << 4;  // CS even -> parity fixed

    auto stage = [&](int bufw) {
        unsigned ob[8];
#pragma unroll
        for (int j = 0; j < 8; ++j)
            ob[j] = __builtin_amdgcn_alignbit(d[j + 1], d[j], sh);
        *(uint4*)&As[bufw][a_row][a_k16]     = aR0;
        *(uint4*)&As[bufw][a_row][a_k16 + 8] = aR1;
        *(uint4*)&Bt[bufw][b_pix][bh * 16]     = *(uint4*)&ob[0];
        *(uint4*)&Bt[bufw][b_pix][bh * 16 + 8] = *(uint4*)&ob[4];
    };

    // prologue: stage tile0 into buf0, issue tile1 loads, barrier
    stage(0);
    loadA(k0 + 32); loadB(k0 + 32);      // Ks >= 64 always (512/2048)
    asm volatile("s_waitcnt lgkmcnt(0)" ::: "memory");
    __builtin_amdgcn_sched_barrier(0);
    __builtin_amdgcn_s_barrier();
    __builtin_amdgcn_sched_barrier(0);

    int buf = 0;
    for (int kt = k0; kt < k0 + Ks; kt += 32) {
        // ---- phase 1: kk=0 ----
        bf16x8 a00 = __builtin_bit_cast(bf16x8, *(const uint4*)&As[buf][wy + l5][l8]);
        bf16x8 a10 = __builtin_bit_cast(bf16x8, *(const uint4*)&As[buf][wy + 32 + l5][l8]);
        bf16x8 b00 = __builtin_bit_cast(bf16x8, *(const uint4*)&Bt[buf][wx + l5][l8]);
        bf16x8 b10 = __builtin_bit_cast(bf16x8, *(const uint4*)&Bt[buf][wx + 32 + l5][l8]);
        __builtin_amdgcn_s_setprio(1);
        acc[0][0] = __builtin_amdgcn_mfma_f32_32x32x16_bf16(a00, b00, acc[0][0], 0, 0, 0);
        acc[0][1] = __builtin_amdgcn_mfma_f32_32x32x16_bf16(a00, b10, acc[0][1], 0, 0, 0);
        acc[1][0] = __builtin_amdgcn_mfma_f32_32x32x16_bf16(a10, b00, acc[1][0], 0, 0, 0);
        acc[1][1] = __builtin_amdgcn_mfma_f32_32x32x16_bf16(a10, b10, acc[1][1], 0, 0, 0);
        __builtin_amdgcn_s_setprio(0);
        // ---- stage tile t+1 (regs loaded last iter), issue t+2 loads ----
        if (kt + 32 < k0 + Ks) {
            stage(buf ^ 1);
            if (kt + 64 < k0 + Ks) { loadA(kt + 64); loadB(kt + 64); }
        }
        // ---- phase 2: kk=1 ----
        bf16x8 a01 = __builtin_bit_cast(bf16x8, *(const uint4*)&As[buf][wy + l5][16 + l8]);
        bf16x8 a11 = __builtin_bit_cast(bf16x8, *(const uint4*)&As[buf][wy + 32 + l5][16 + l8]);
        bf16x8 b01 = __builtin_bit_cast(bf16x8, *(const uint4*)&Bt[buf][wx + l5][16 + l8]);
        bf16x8 b11 = __builtin_bit_cast(bf16x8, *(const uint4*)&Bt[buf][wx + 32 + l5][16 + l8]);
        __builtin_amdgcn_s_setprio(1);
        acc[0][0] = __builtin_amdgcn_mfma_f32_32x32x16_bf16(a01, b01, acc[0][0], 0, 0, 0);
        acc[0][1] = __builtin_amdgcn_mfma_f32_32x32x16_bf16(a01, b11, acc[0][1], 0, 0, 0);
        acc[1][0] = __builtin_amdgcn_mfma_f32_32x32x16_bf16(a11, b01, acc[1][0], 0, 0, 0);
        acc[1][1] = __builtin_amdgcn_mfma_f32_32x32x16_bf16(a11, b11, acc[1][1], 0, 0, 0);
        __builtin_amdgcn_s_setprio(0);
        // ---- end-of-iter raw barrier (no vmcnt drain: prefetch stays live) ----
        asm volatile("s_waitcnt lgkmcnt(0)" ::: "memory");
        __builtin_amdgcn_sched_barrier(0);
        __builtin_amdgcn_s_barrier();
        __builtin_amdgcn_sched_barrier(0);
        buf ^= 1;
    }

    float* Pp = P + (size_t)zt * Mpad * NPIX;
#pragma unroll
    for (int i = 0; i < 2; ++i) {
        const int mb = mbase + wy + i * 32 + (lane >> 5) * 4;
#pragma unroll
        for (int j = 0; j < 2; ++j) {
            const int pp = pbase + wx + j * 32 + l5;
            if (pp < NPIX) {
#pragma unroll
                for (int r = 0; r < 16; ++r) {
                    const int m = mb + (r & 3) + 8 * (r >> 2);
                    Pp[(size_t)m * NPIX + pp] = acc[i][j][r];
                }
            }
        }
    }
}

// conv1 dual reduce: both paths' partials + bias -> bf16 padded layouts.
// 4 pixels per thread, float4 partial loads. halfGrid = 475 blocks per path.
__global__ void reduce_pad_dual(
    const float* __restrict__ P0, const float* __restrict__ bias0,
    unsigned short* __restrict__ out0, int CS0, int yM0, int xM0,
    const float* __restrict__ P1, const float* __restrict__ bias1,
    unsigned short* __restrict__ out1, int CS1, int yM1, int xM1,
    int Mpad, int nsplit, int M, int halfGrid)
{
    int b = blockIdx.x;
    const float* P; const float* bias; unsigned short* outb;
    int CS, yMul, xMul;
    if (b < halfGrid) { P = P0; bias = bias0; outb = out0; CS = CS0; yMul = yM0; xMul = xM0; }
    else { b -= halfGrid; P = P1; bias = bias1; outb = out1; CS = CS1; yMul = yM1; xMul = xM1; }
    int idx4 = b * 256 + threadIdx.x;
    if (idx4 >= M * 475) return;
    int o = idx4 / 475;
    int p = (idx4 - o * 475) * 4;
    float bv = bias[o];
    f32x4 s = {bv, bv, bv, bv};
    for (int sp = 0; sp < nsplit; ++sp)
        s += *(const f32x4*)&P[((size_t)sp * Mpad + o) * NPIX + p];
#pragma unroll
    for (int e = 0; e < 4; ++e) {
        int pe = p + e;
        int y = pe / FW, x = pe - y * FW;
        outb[(size_t)o * CS + y * yMul + x * xMul + 7] = f2b(s[e]);
    }
}

// conv2 dual reduce: h = relu(sum P0 + sum P1 + b_col + b_row), fp32 raster.
__global__ void reduce_bias_dual(
    const float* __restrict__ P0, const float* __restrict__ P1,
    int Mpad, int nsplit,
    const float* __restrict__ bias0, const float* __restrict__ bias1,
    int M, float* __restrict__ outf)
{
    int idx4 = blockIdx.x * 256 + threadIdx.x;
    if (idx4 >= M * 475) return;
    int o = idx4 / 475;
    int p = (idx4 - o * 475) * 4;
    float bv = bias0[o] + bias1[o];
    f32x4 s = {bv, bv, bv, bv};
    for (int sp = 0; sp < nsplit; ++sp) {
        s += *(const f32x4*)&P0[((size_t)sp * Mpad + o) * NPIX + p];
        s += *(const f32x4*)&P1[((size_t)sp * Mpad + o) * NPIX + p];
    }
#pragma unroll
    for (int e = 0; e < 4; ++e) s[e] = fmaxf(s[e], 0.f);
    *(f32x4*)&outf[(size_t)o * NPIX + p] = s;
}

// ---------------------------------------------------------------------------
// PSROI bilinear pooling (fp32 h) -> bf16 pooled [512][512] zero-padded
// ---------------------------------------------------------------------------
__global__ __launch_bounds__(512) void pool_kernel(
    const float* __restrict__ h, const float* __restrict__ rois,
    unsigned short* __restrict__ pooledb)
{
    int n = blockIdx.x;
    int k = threadIdx.x;
    if (k >= 490) {
        pooledb[(size_t)n * 512 + k] = 0;
        return;
    }
    float x1 = rois[n * 4 + 0], y1 = rois[n * 4 + 1];
    float x2 = rois[n * 4 + 2], y2 = rois[n * 4 + 3];
    float xmin = x1 * (1.f / 16.f) / 50.f;
    float ymin = y1 * (1.f / 16.f) / 38.f;
    float xmax = x2 * (1.f / 16.f) / 50.f;
    float ymax = y2 * (1.f / 16.f) / 38.f;
    float step_x = (xmax - xmin) / 7.f;
    float step_y = (ymax - ymin) / 7.f;
    int bin = k / 10;
    int bi = bin / 7, bj = bin - bi * 7;
    const float* ch = h + (size_t)k * NPIX;
    float m = -INFINITY;
#pragma unroll
    for (int sy = 0; sy < 2; ++sy) {
        float yv = (ymin + (float)(bi + sy) * step_y) * 37.f;
        float y0 = floorf(yv);
        float fy = yv - y0;
        int yi0 = min(max((int)y0, 0), 37);
        int yi1 = min(max((int)y0 + 1, 0), 37);
#pragma unroll
        for (int sx = 0; sx < 2; ++sx) {
            float xv = (xmin + (float)(bj + sx) * step_x) * 49.f;
            float x0 = floorf(xv);
            float fx = xv - x0;
            int xi0 = min(max((int)x0, 0), 49);
            int xi1 = min(max((int)x0 + 1, 0), 49);
            float v00 = ch[yi0 * FW + xi0], v01 = ch[yi0 * FW + xi1];
            float v10 = ch[yi1 * FW + xi0], v11 = ch[yi1 * FW + xi1];
            float top = v00 + (v01 - v00) * fx;
            float bot = v10 + (v11 - v10) * fx;
            float val = top + (bot - top) * fy;
            m = fmaxf(m, val);
        }
    }
    pooledb[(size_t)n * 512 + k] = f2b(m);
}

// ---------------------------------------------------------------------------
// bf16 MFMA NT GEMM (FC): A = weights [M][Kld], B = acts [512][Kld], split-K.
// ---------------------------------------------------------------------------
__device__ __forceinline__ void fc_body(
    const unsigned short* __restrict__ Wb,
    const unsigned short* __restrict__ Act,
    float* __restrict__ P, int M, int Kld, int Mpad, int nsplit,
    int bx, int by, int bz,
    unsigned short (*As)[40], unsigned short (*Bs)[40])
{
    const int Ks = Kld / nsplit;
    const int k0 = bz * Ks;
    const int tid  = threadIdx.x;
    const int lane = tid & 63;
    const int wave = tid >> 6;
    const int mbase = bx * 64;
    const int nbase = by * 64;

    const int s_r  = tid >> 2;
    const int s_k8 = (tid & 3) << 3;
    const int a_row = mbase + s_r;
    const bool a_ok = a_row < M;
    const unsigned short* Abase = Wb + (size_t)a_row * Kld + s_k8;
    const unsigned short* Bbase = Act + (size_t)(nbase + s_r) * Kld + s_k8;

    f32x4 acc[2][2];
#pragma unroll
    for (int i = 0; i < 2; ++i)
#pragma unroll
        for (int j = 0; j < 2; ++j)
#pragma unroll
            for (int r = 0; r < 4; ++r) acc[i][j][r] = 0.f;

    const int mh = (wave >> 1) * 32;
    const int nh = (wave & 1) * 32;
    const int lm = lane & 15;
    const int l8 = (lane >> 4) * 8;

    uint4 aReg, bReg;
    if (a_ok) aReg = *(const uint4*)(Abase + k0);
    else { aReg.x = aReg.y = aReg.z = aReg.w = 0u; }
    bReg = *(const uint4*)(Bbase + k0);

    for (int kt = k0; kt < k0 + Ks; kt += 32) {
        *(uint4*)&As[s_r][s_k8] = aReg;
        *(uint4*)&Bs[s_r][s_k8] = bReg;
        __syncthreads();

        if (kt + 32 < k0 + Ks) {
            if (a_ok) aReg = *(const uint4*)(Abase + kt + 32);
            bReg = *(const uint4*)(Bbase + kt + 32);
        }

        bf16x8 a0 = __builtin_bit_cast(bf16x8, *(const uint4*)&As[mh + lm][l8]);
        bf16x8 a1 = __builtin_bit_cast(bf16x8, *(const uint4*)&As[mh + 16 + lm][l8]);
        bf16x8 b0 = __builtin_bit_cast(bf16x8, *(const uint4*)&Bs[nh + lm][l8]);
        bf16x8 b1 = __builtin_bit_cast(bf16x8, *(const uint4*)&Bs[nh + 16 + lm][l8]);

        acc[0][0] = __builtin_amdgcn_mfma_f32_16x16x32_bf16(a0, b0, acc[0][0], 0, 0, 0);
        acc[0][1] = __builtin_amdgcn_mfma_f32_16x16x32_bf16(a0, b1, acc[0][1], 0, 0, 0);
        acc[1][0] = __builtin_amdgcn_mfma_f32_16x16x32_bf16(a1, b0, acc[1][0], 0, 0, 0);
        acc[1][1] = __builtin_amdgcn_mfma_f32_16x16x32_bf16(a1, b1, acc[1][1], 0, 0, 0);
        __syncthreads();
    }

#pragma unroll
    for (int ms = 0; ms < 2; ++ms)
#pragma unroll
        for (int ns = 0; ns < 2; ++ns) {
            int n  = nbase + nh + ns * 16 + lm;
            int m0 = mbase + mh + ms * 16 + (lane >> 4) * 4;
            float* Pp = P + ((size_t)bz * NROIS + n) * Mpad + m0;
            *(f32x4*)Pp = acc[ms][ns];
        }
}

// fc1 WITHOUT split-K: full K=512, fused bias+relu+bf16 epilogue.
__global__ __launch_bounds__(256) void fc1_fused(
    const unsigned short* __restrict__ Wb,
    const unsigned short* __restrict__ Act,
    const float* __restrict__ bias,
    unsigned short* __restrict__ outb)
{
    __shared__ unsigned short As[64][40];
    __shared__ unsigned short Bs[64][40];
    const int tid  = threadIdx.x;
    const int lane = tid & 63;
    const int wave = tid >> 6;
    const int mbase = blockIdx.x * 64;
    const int nbase = blockIdx.y * 64;

    const int s_r  = tid >> 2;
    const int s_k8 = (tid & 3) << 3;
    const unsigned short* Abase = Wb + (size_t)(mbase + s_r) * 512 + s_k8;
    const unsigned short* Bbase = Act + (size_t)(nbase + s_r) * 512 + s_k8;

    f32x4 acc[2][2];
#pragma unroll
    for (int i = 0; i < 2; ++i)
#pragma unroll
        for (int j = 0; j < 2; ++j)
#pragma unroll
            for (int r = 0; r < 4; ++r) acc[i][j][r] = 0.f;

    const int mh = (wave >> 1) * 32;
    const int nh = (wave & 1) * 32;
    const int lm = lane & 15;
    const int l8 = (lane >> 4) * 8;

    uint4 aReg = *(const uint4*)(Abase);
    uint4 bReg = *(const uint4*)(Bbase);

    for (int kt = 0; kt < 512; kt += 32) {
        *(uint4*)&As[s_r][s_k8] = aReg;
        *(uint4*)&Bs[s_r][s_k8] = bReg;
        __syncthreads();

        if (kt + 32 < 512) {
            aReg = *(const uint4*)(Abase + kt + 32);
            bReg = *(const uint4*)(Bbase + kt + 32);
        }

        bf16x8 a0 = __builtin_bit_cast(bf16x8, *(const uint4*)&As[mh + lm][l8]);
        bf16x8 a1 = __builtin_bit_cast(bf16x8, *(const uint4*)&As[mh + 16 + lm][l8]);
        bf16x8 b0 = __builtin_bit_cast(bf16x8, *(const uint4*)&Bs[nh + lm][l8]);
        bf16x8 b1 = __builtin_bit_cast(bf16x8, *(const uint4*)&Bs[nh + 16 + lm][l8]);

        acc[0][0] = __builtin_amdgcn_mfma_f32_16x16x32_bf16(a0, b0, acc[0][0], 0, 0, 0);
        acc[0][1] = __builtin_amdgcn_mfma_f32_16x16x32_bf16(a0, b1, acc[0][1], 0, 0, 0);
        acc[1][0] = __builtin_amdgcn_mfma_f32_16x16x32_bf16(a1, b0, acc[1][0], 0, 0, 0);
        acc[1][1] = __builtin_amdgcn_mfma_f32_16x16x32_bf16(a1, b1, acc[1][1], 0, 0, 0);
        __syncthreads();
    }

#pragma unroll
    for (int ms = 0; ms < 2; ++ms)
#pragma unroll
        for (int ns = 0; ns < 2; ++ns) {
            int n  = nbase + nh + ns * 16 + lm;
            int m0 = mbase + mh + ms * 16 + (lane >> 4) * 4;
            ushort4 v;
#pragma unroll
            for (int r = 0; r < 4; ++r) {
                float s = acc[ms][ns][r] + bias[m0 + r];
                s = fmaxf(s, 0.f);
                ((unsigned short*)&v)[r] = f2b(s);
            }
            *(ushort4*)(outb + (size_t)n * 2048 + m0) = v;
        }
}

// loc (192 blocks: 6x8x4) + score (128 blocks: 2x8x8) in one dispatch
__global__ __launch_bounds__(256) void fc_mfma_dual(
    const unsigned short* __restrict__ Wloc,
    const unsigned short* __restrict__ Wscore,
    const unsigned short* __restrict__ Act,
    float* __restrict__ Ploc, float* __restrict__ Pscore)
{
    __shared__ unsigned short As[64][40];
    __shared__ unsigned short Bs[64][40];
    int id = blockIdx.x;
    if (id < 192) {
        int bx = id % 6, by = (id / 6) % 8, bz = id / 48;
        fc_body(Wloc, Act, Ploc, 324, 2048, 384, 4, bx, by, bz, As, Bs);
    } else {
        int l = id - 192;
        int bx = l % 2, by = (l / 2) % 8, bz = l / 16;
        fc_body(Wscore, Act, Pscore, 81, 2048, 128, 8, bx, by, bz, As, Bs);
    }
}

// loc (648 blocks) + score (162 blocks) reduce in one dispatch
__global__ void fc_reduce_dual(
    const float* __restrict__ Ploc, const float* __restrict__ Pscore,
    const float* __restrict__ b_loc, const float* __restrict__ b_score,
    float* __restrict__ outLoc, float* __restrict__ outScore)
{
    int b = blockIdx.x;
    if (b < 648) {
        int idx = b * 256 + threadIdx.x;
        if (idx >= NROIS * 324) return;
        int n = idx / 324, m = idx - n * 324;
        float s = b_loc[m];
        for (int sp = 0; sp < 4; ++sp)
            s += Ploc[((size_t)sp * NROIS + n) * 384 + m];
        outLoc[idx] = s;
    } else {
        int idx = (b - 648) * 256 + threadIdx.x;
        if (idx >= NROIS * 81) return;
        int n = idx / 81, m = idx - n * 81;
        float s = b_score[m];
        for (int sp = 0; sp < 8; ++sp)
            s += Pscore[((size_t)sp * NROIS + n) * 128 + m];
        outScore[idx] = s;
    }
}

extern "C" void kernel_launch(void* const* d_in, const int* in_sizes, int n_in,
                              void* d_out, int out_size, void* d_ws, size_t ws_size,
                              hipStream_t stream) {
    const float* x         = (const float*)d_in[0];
    const float* rois      = (const float*)d_in[1];
    const float* w_col_max = (const float*)d_in[2];
    const float* b_col_max = (const float*)d_in[3];
    const float* w_col     = (const float*)d_in[4];
    const float* b_col     = (const float*)d_in[5];
    const float* w_row_max = (const float*)d_in[6];
    const float* b_row_max = (const float*)d_in[7];
    const float* w_row     = (const float*)d_in[8];
    const float* b_row     = (const float*)d_in[9];
    const float* w_fc1     = (const float*)d_in[10];
    const float* b_fc1     = (const float*)d_in[11];
    const float* w_score   = (const float*)d_in[12];
    const float* b_score   = (const float*)d_in[13];
    const float* w_loc     = (const float*)d_in[14];
    const float* b_loc     = (const float*)d_in[15];

    float* part0 = (float*)d_ws;                       // 7,782,400 f = 31.1 MB
    float* part1 = part0 + 7782400;                    // 7,782,400 f = 31.1 MB
    unsigned short* XvU   = (unsigned short*)(part1 + 7782400); // 5,427,264
    unsigned short* XhU   = XvU + 5427264;             // 5,058,624
    unsigned short* wbig0 = XhU + 5058624;             // 8,388,608 (col-max)
    unsigned short* wbig1 = wbig0 + 8388608;           // 8,388,608 (row-max)
    unsigned short* wc16  = wbig1 + 8388608;           // 2,007,040
    unsigned short* wr16  = wc16 + 2007040;            // 2,007,040
    unsigned short* c1colb= wr16 + 2007040;            //   632,384
    unsigned short* c1rowb= c1colb + 632384;           //   678,464
    unsigned short* wfc1b = c1rowb + 678464;           // 1,048,576
    unsigned short* pooledb = wfc1b + 1048576;         //   262,144
    unsigned short* fc1b  = pooledb + 262144;          // 1,048,576
    unsigned short* wlocb = fc1b + 1048576;            //   663,552
    unsigned short* wscoreb = wlocb + 663552;          //   165,888
    float* h = (float*)XhU;                            // alias (XhU dead after conv1)
    // total ~134 MB

    // ---- all prep in ONE dispatch ----
    prep_all<<<PREP_BLOCKS, 256, 0, stream>>>(
        x, w_col_max, w_row_max, w_col, w_row, w_fc1, w_loc, w_score,
        XvU, XhU, c1colb, wbig0, wbig1, wc16, wr16, wfc1b, wlocb, wscoreb);

    // ---- conv1 col(vertical)+row(horizontal) fused: 2 x 480 blocks ----
    conv_dual<<<960, 256, 0, stream>>>(
        wbig0, XvU, part0, CSV, 1, 53,
        wbig1, XhU, part1, CSH, 65, 1,
        256, 32768, 256, 15, 4, 1, 5, 480);
    reduce_pad_dual<<<950, 256, 0, stream>>>(
        part0, b_col_max, c1colb, CSH, 65, 1,
        part1, b_row_max, c1rowb, CSV, 1, 53,
        256, 16, 256, 475);

    // ---- conv2 col(horizontal)+row(vertical) fused ----
    conv_dual<<<960, 256, 0, stream>>>(
        wc16, c1colb, part0, CSH, 65, 1,
        wr16, c1rowb, part1, CSV, 1, 53,
        490, 4096, 512, 7, 3, 3, 5, 480);
    reduce_bias_dual<<<910, 256, 0, stream>>>(
        part0, part1, 512, 8, b_col, b_row, 490, h);

    // ---- PSROI pooling ----
    pool_kernel<<<512, 512, 0, stream>>>(h, rois, pooledb);

    float* out = (float*)d_out;
    // fc1: M=2048, K=512, NO split, fused bias+relu+bf16 epilogue
    fc1_fused<<<dim3(32, 8), 256, 0, stream>>>(wfc1b, pooledb, b_fc1, fc1b);

    // roi_cls_locs (M=324, split 4) + roi_scores (M=81, split 8) fused
    float* Ploc   = part0;                 // 4*512*384 = 786,432 f
    float* Pscore = part0 + 786432;        // 8*512*128 = 524,288 f
    fc_mfma_dual<<<320, 256, 0, stream>>>(wlocb, wscoreb, fc1b, Ploc, Pscore);
    fc_reduce_dual<<<810, 256, 0, stream>>>(Ploc, Pscore, b_loc, b_score,
                                            out, out + 512 * 324);
}